// Round 1
// baseline (2100.182 us; speedup 1.0000x reference)
//
#include <hip/hip_runtime.h>
#include <hip/hip_bf16.h>
#include <math.h>

#define B_ 2
#define T_ 2048
#define C_ 768
#define H_ 12
#define D_ 64

typedef __attribute__((ext_vector_type(8))) short short8;
typedef __attribute__((ext_vector_type(4))) float f32x4;

__device__ inline unsigned short f2bf(float f) {
    unsigned int x = __float_as_uint(f);
    unsigned int r = x + 0x7FFFu + ((x >> 16) & 1u);
    return (unsigned short)(r >> 16);
}

// coherence table: coh[dd] = mean_m cos(dd * theta_m), theta_m = 10000^(-m/32), m=0..31
__global__ void coh_kernel(float* __restrict__ coh) {
    int dd = blockIdx.x * blockDim.x + threadIdx.x;
    if (dd >= T_) return;
    float s = 0.f;
    for (int m = 0; m < 32; ++m) {
        float theta = powf(10000.f, -(float)m / 32.f);
        s += cosf((float)dd * theta);
    }
    coh[dd] = s * (1.f / 32.f);
}

__global__ void tobf16_kernel(const float* __restrict__ src,
                              unsigned short* __restrict__ dst, int n4) {
    int i = blockIdx.x * blockDim.x + threadIdx.x;
    if (i >= n4) return;
    float4 v = ((const float4*)src)[i];
    ushort4 o;
    o.x = f2bf(v.x); o.y = f2bf(v.y); o.z = f2bf(v.z); o.w = f2bf(v.w);
    ((ushort4*)dst)[i] = o;
}

// C[m,n] = sum_k A[m,k] * Bw[n,k]   (NT GEMM, bf16 in, f32 out)
// one wave = one 16x16 tile; 4 waves/block along M.
__global__ __launch_bounds__(256) void gemm_nt_kernel(const unsigned short* __restrict__ A,
                                                      const unsigned short* __restrict__ Bw,
                                                      float* __restrict__ C,
                                                      int M, int N, int K) {
    int w = threadIdx.x >> 6;
    int lane = threadIdx.x & 63;
    int tm = blockIdx.x * 4 + w;
    int tn = blockIdx.y;
    int rc = lane & 15;      // A-row / B-col within tile
    int kg = lane >> 4;      // k-group (8 consecutive k each)
    const unsigned short* ap = A + (size_t)(tm * 16 + rc) * K + kg * 8;
    const unsigned short* bp = Bw + (size_t)(tn * 16 + rc) * K + kg * 8;
    f32x4 acc = {0.f, 0.f, 0.f, 0.f};
    for (int k0 = 0; k0 < K; k0 += 32) {
        short8 a = *(const short8*)(ap + k0);
        short8 b = *(const short8*)(bp + k0);
        acc = __builtin_amdgcn_mfma_f32_16x16x32_bf16(a, b, acc, 0, 0, 0);
    }
    // D layout: col = lane&15, row = (lane>>4)*4 + r
    int orow = tm * 16 + kg * 4;
    int ocol = tn * 16 + rc;
    #pragma unroll
    for (int r = 0; r < 4; ++r) C[(size_t)(orow + r) * N + ocol] = acc[r];
}

// in-place rotary + rmsnorm over rows of 64; buf layout (b, t, h, d); one wave per row
__global__ __launch_bounds__(256) void rope_rms_kernel(float* __restrict__ buf,
                                                       const float* __restrict__ cosb,
                                                       const float* __restrict__ sinb) {
    int r = blockIdx.x * 4 + (threadIdx.x >> 6);   // row over B*T*H
    int lane = threadIdx.x & 63;
    int t = (r / H_) % T_;
    float* p = buf + (size_t)r * D_;
    float val = p[lane];
    float part = __shfl_xor(val, 32);
    int cs = lane & 31;
    float c = cosb[t * 32 + cs];
    float s = sinb[t * 32 + cs];
    // lane<32: x1*c + x2*s ; lane>=32: -x1*s + x2*c
    float o = val * c + part * (lane < 32 ? s : -s);
    float ss = o * o;
    #pragma unroll
    for (int m = 32; m >= 1; m >>= 1) ss += __shfl_xor(ss, m);
    float rn = rsqrtf(ss * (1.f / 64.f) + 1.1920929e-07f);
    p[lane] = o * rn;
}

// thread-per-(b,h,q)-row attention; fixed m=0 softmax (safe: |s|<=12)
__global__ __launch_bounds__(256, 1) void attn_kernel(const float* __restrict__ qn,
                                                      const float* __restrict__ kn,
                                                      const float* __restrict__ vn,
                                                      const float* __restrict__ coh,
                                                      const float* __restrict__ beta,
                                                      unsigned short* __restrict__ yb) {
    int gid = blockIdx.x * blockDim.x + threadIdx.x;
    int b = gid / (H_ * T_);
    int h = (gid / T_) % H_;
    int q = gid % T_;
    const float4* qp = (const float4*)(qn + ((size_t)(b * T_ + q) * H_ + h) * D_);
    float4 qv[16];
    #pragma unroll
    for (int i = 0; i < 16; ++i) qv[i] = qp[i];
    float4 acc[16];
    #pragma unroll
    for (int i = 0; i < 16; ++i) acc[i] = make_float4(0.f, 0.f, 0.f, 0.f);
    float Za = 0.f, Zc = 0.f;
    float bh = beta[h];
    const float* kbase = kn + ((size_t)b * T_ * H_ + h) * D_;
    const float* vbase = vn + ((size_t)b * T_ * H_ + h) * D_;
    for (int j = 0; j < T_; ++j) {
        const float4* kp = (const float4*)(kbase + (size_t)j * H_ * D_);
        float s0 = 0.f, s1 = 0.f, s2 = 0.f, s3 = 0.f;
        #pragma unroll
        for (int i = 0; i < 16; ++i) {
            float4 kk = kp[i];
            s0 += qv[i].x * kk.x;
            s1 += qv[i].y * kk.y;
            s2 += qv[i].z * kk.z;
            s3 += qv[i].w * kk.w;
        }
        int dd = q - j; if (dd < 0) dd = -dd;
        float cf = 1.f + bh * coh[dd];
        float s = (s0 + s1 + s2 + s3) * 0.125f * cf;
        float e = __expf(s);
        Za += e;
        if (j <= q) {
            Zc += e;
            const float4* vp = (const float4*)(vbase + (size_t)j * H_ * D_);
            #pragma unroll
            for (int i = 0; i < 16; ++i) {
                float4 vv = vp[i];
                acc[i].x += e * vv.x; acc[i].y += e * vv.y;
                acc[i].z += e * vv.z; acc[i].w += e * vv.w;
            }
        }
    }
    float inv = 1.f / (Zc + 1e-8f * Za);
    unsigned short* yp = yb + ((size_t)(b * T_ + q) * H_ + h) * D_;
    #pragma unroll
    for (int i = 0; i < 16; ++i) {
        float4 a = acc[i];
        ushort4 o;
        o.x = f2bf(a.x * inv); o.y = f2bf(a.y * inv);
        o.z = f2bf(a.z * inv); o.w = f2bf(a.w * inv);
        *(ushort4*)(yp + i * 4) = o;
    }
}

extern "C" void kernel_launch(void* const* d_in, const int* in_sizes, int n_in,
                              void* d_out, int out_size, void* d_ws, size_t ws_size,
                              hipStream_t stream) {
    const float* x    = (const float*)d_in[0];
    const float* cosb = (const float*)d_in[1];
    const float* sinb = (const float*)d_in[2];
    const float* Wq   = (const float*)d_in[3];
    const float* Wk   = (const float*)d_in[4];
    const float* Wv   = (const float*)d_in[5];
    const float* Wo   = (const float*)d_in[6];
    const float* beta = (const float*)d_in[7];
    float* out = (float*)d_out;

    char* ws = (char*)d_ws;
    float*          qraw = (float*)(ws + 0);
    float*          kraw = (float*)(ws + 12582912);
    float*          vraw = (float*)(ws + 25165824);
    unsigned short* yb   = (unsigned short*)(ws + 37748736);
    unsigned short* xb   = (unsigned short*)(ws + 44040192);
    unsigned short* wqb  = (unsigned short*)(ws + 50331648);
    unsigned short* wkb  = (unsigned short*)(ws + 51511296);
    unsigned short* wvb  = (unsigned short*)(ws + 52690944);
    unsigned short* wob  = (unsigned short*)(ws + 53870592);
    float*          coh  = (float*)(ws + 55050240);

    coh_kernel<<<T_ / 256, 256, 0, stream>>>(coh);

    int nx4 = (B_ * T_ * C_) / 4;   // 786432
    tobf16_kernel<<<nx4 / 256, 256, 0, stream>>>(x, xb, nx4);
    int nw4 = (C_ * C_) / 4;        // 147456
    tobf16_kernel<<<nw4 / 256, 256, 0, stream>>>(Wq, wqb, nw4);
    tobf16_kernel<<<nw4 / 256, 256, 0, stream>>>(Wk, wkb, nw4);
    tobf16_kernel<<<nw4 / 256, 256, 0, stream>>>(Wv, wvb, nw4);
    tobf16_kernel<<<nw4 / 256, 256, 0, stream>>>(Wo, wob, nw4);

    dim3 gg(64, 48);   // (M/16/4, N/16)
    gemm_nt_kernel<<<gg, 256, 0, stream>>>(xb, wqb, qraw, 4096, 768, 768);
    gemm_nt_kernel<<<gg, 256, 0, stream>>>(xb, wkb, kraw, 4096, 768, 768);
    gemm_nt_kernel<<<gg, 256, 0, stream>>>(xb, wvb, vraw, 4096, 768, 768);

    rope_rms_kernel<<<(B_ * T_ * H_) / 4, 256, 0, stream>>>(qraw, cosb, sinb);
    rope_rms_kernel<<<(B_ * T_ * H_) / 4, 256, 0, stream>>>(kraw, cosb, sinb);

    attn_kernel<<<(B_ * H_ * T_) / 256, 256, 0, stream>>>(qraw, kraw, vraw, coh, beta, yb);

    gemm_nt_kernel<<<gg, 256, 0, stream>>>(yb, wob, out, 4096, 768, 768);
}

// Round 2
// 499.904 us; speedup vs baseline: 4.2012x; 4.2012x over previous
//
#include <hip/hip_runtime.h>
#include <hip/hip_bf16.h>
#include <math.h>

#define B_ 2
#define T_ 2048
#define C_ 768
#define H_ 12
#define D_ 64

typedef __attribute__((ext_vector_type(8))) short short8;
typedef __attribute__((ext_vector_type(4))) float f32x4;

__device__ inline unsigned short f2bf(float f) {
    unsigned int x = __float_as_uint(f);
    unsigned int r = x + 0x7FFFu + ((x >> 16) & 1u);
    return (unsigned short)(r >> 16);
}

// coherence table: coh[dd] = mean_m cos(dd * theta_m), theta_m = 10000^(-m/32)
__global__ void coh_kernel(float* __restrict__ coh) {
    int dd = blockIdx.x * blockDim.x + threadIdx.x;
    if (dd >= T_) return;
    float s = 0.f;
    for (int m = 0; m < 32; ++m) {
        float theta = powf(10000.f, -(float)m / 32.f);
        s += cosf((float)dd * theta);
    }
    coh[dd] = s * (1.f / 32.f);
}

__global__ void tobf16_kernel(const float* __restrict__ src,
                              unsigned short* __restrict__ dst, int n4) {
    int i = blockIdx.x * blockDim.x + threadIdx.x;
    if (i >= n4) return;
    float4 v = ((const float4*)src)[i];
    ushort4 o;
    o.x = f2bf(v.x); o.y = f2bf(v.y); o.z = f2bf(v.z); o.w = f2bf(v.w);
    ((ushort4*)dst)[i] = o;
}

// C[m,n] = sum_k A[m,k] * Bw[n,k]   (NT GEMM, bf16 in, f32 out)
__global__ __launch_bounds__(256) void gemm_nt_kernel(const unsigned short* __restrict__ A,
                                                      const unsigned short* __restrict__ Bw,
                                                      float* __restrict__ C,
                                                      int M, int N, int K) {
    int w = threadIdx.x >> 6;
    int lane = threadIdx.x & 63;
    int tm = blockIdx.x * 4 + w;
    int tn = blockIdx.y;
    int rc = lane & 15;
    int kg = lane >> 4;
    const unsigned short* ap = A + (size_t)(tm * 16 + rc) * K + kg * 8;
    const unsigned short* bp = Bw + (size_t)(tn * 16 + rc) * K + kg * 8;
    f32x4 acc = {0.f, 0.f, 0.f, 0.f};
    for (int k0 = 0; k0 < K; k0 += 32) {
        short8 a = *(const short8*)(ap + k0);
        short8 b = *(const short8*)(bp + k0);
        acc = __builtin_amdgcn_mfma_f32_16x16x32_bf16(a, b, acc, 0, 0, 0);
    }
    int orow = tm * 16 + kg * 4;
    int ocol = tn * 16 + rc;
    #pragma unroll
    for (int r = 0; r < 4; ++r) C[(size_t)(orow + r) * N + ocol] = acc[r];
}

// V GEMM: writes bf16 transposed per-head: vt[(b*H+h)*64 + d][t]  (b,h,d,t)
__global__ __launch_bounds__(256) void gemm_nt_vt_kernel(const unsigned short* __restrict__ A,
                                                         const unsigned short* __restrict__ Bw,
                                                         unsigned short* __restrict__ vt,
                                                         int M, int N, int K) {
    int w = threadIdx.x >> 6;
    int lane = threadIdx.x & 63;
    int tm = blockIdx.x * 4 + w;
    int tn = blockIdx.y;
    int rc = lane & 15;
    int kg = lane >> 4;
    const unsigned short* ap = A + (size_t)(tm * 16 + rc) * K + kg * 8;
    const unsigned short* bp = Bw + (size_t)(tn * 16 + rc) * K + kg * 8;
    f32x4 acc = {0.f, 0.f, 0.f, 0.f};
    for (int k0 = 0; k0 < K; k0 += 32) {
        short8 a = *(const short8*)(ap + k0);
        short8 b = *(const short8*)(bp + k0);
        acc = __builtin_amdgcn_mfma_f32_16x16x32_bf16(a, b, acc, 0, 0, 0);
    }
    int orow = tm * 16 + kg * 4;        // m = b*T + t, 4 consecutive t
    int ocol = tn * 16 + rc;            // n = h*64 + d
    int b = orow / T_;
    int t = orow % T_;
    int h = ocol >> 6, d = ocol & 63;
    ushort4 o;
    o.x = f2bf(acc[0]); o.y = f2bf(acc[1]); o.z = f2bf(acc[2]); o.w = f2bf(acc[3]);
    *(ushort4*)(vt + ((size_t)(b * H_ + h) * 64 + d) * T_ + t) = o;
}

// rotary + rmsnorm; reads (b,t,h,d) f32, writes (b,h,t,d) bf16, folds `scale`
__global__ __launch_bounds__(256) void rope_rms_t_kernel(const float* __restrict__ buf,
                                                         const float* __restrict__ cosb,
                                                         const float* __restrict__ sinb,
                                                         unsigned short* __restrict__ obf,
                                                         float scale) {
    int r = blockIdx.x * 4 + (threadIdx.x >> 6);   // row over (b,t,h)
    int lane = threadIdx.x & 63;
    int b = r / (T_ * H_);
    int t = (r / H_) % T_;
    int h = r % H_;
    const float* p = buf + (size_t)r * D_;
    float val = p[lane];
    float part = __shfl_xor(val, 32);
    int cs = lane & 31;
    float c = cosb[t * 32 + cs];
    float s = sinb[t * 32 + cs];
    float o = val * c + part * (lane < 32 ? s : -s);
    float ss = o * o;
    #pragma unroll
    for (int m = 32; m >= 1; m >>= 1) ss += __shfl_xor(ss, m);
    float rn = rsqrtf(ss * (1.f / 64.f) + 1.1920929e-07f);
    obf[(((size_t)b * H_ + h) * T_ + t) * D_ + lane] = f2bf(o * rn * scale);
}

// flash attention: block = (b,h, 64 q-rows), 4 waves x 16 q-rows
__global__ __launch_bounds__(256) void attn_flash_kernel(const unsigned short* __restrict__ qbf,
                                                         const unsigned short* __restrict__ kbf,
                                                         const unsigned short* __restrict__ vt,
                                                         const float* __restrict__ coh,
                                                         const float* __restrict__ beta,
                                                         unsigned short* __restrict__ yb) {
    __shared__ float cfl[T_];
    __shared__ unsigned short plds[4][16][40];
    int bh = blockIdx.x >> 5;
    int b = bh / H_, h = bh % H_;
    int tq = (blockIdx.x & 31) * 64;
    int w = threadIdx.x >> 6, lane = threadIdx.x & 63;
    int rc = lane & 15, kg = lane >> 4;

    float bv = beta[h];
    for (int i = threadIdx.x; i < T_; i += 256) cfl[i] = 1.f + bv * coh[i];
    __syncthreads();

    const unsigned short* qb = qbf + (((size_t)bh * T_) + tq + w * 16) * 64;
    const unsigned short* kb = kbf + (size_t)bh * T_ * 64;
    const unsigned short* vb = vt + (size_t)bh * 64 * T_;

    short8 qlo = *(const short8*)(qb + rc * 64 + kg * 8);
    short8 qhi = *(const short8*)(qb + rc * 64 + 32 + kg * 8);

    f32x4 acc[4];
    float za[4], zc[4];
    #pragma unroll
    for (int i = 0; i < 4; ++i) { acc[i] = (f32x4){0.f, 0.f, 0.f, 0.f}; za[i] = 0.f; zc[i] = 0.f; }

    int qbase = tq + w * 16;
    int q0 = qbase + kg * 4;
    int nPV = ((qbase + 15) >> 5) + 1;
    const f32x4 z0 = {0.f, 0.f, 0.f, 0.f};

    for (int jb = 0; jb < nPV; ++jb) {
        int tj = jb * 32;
        short8 b00 = *(const short8*)(kb + (tj + rc) * 64 + kg * 8);
        short8 b01 = *(const short8*)(kb + (tj + rc) * 64 + 32 + kg * 8);
        short8 b10 = *(const short8*)(kb + (tj + 16 + rc) * 64 + kg * 8);
        short8 b11 = *(const short8*)(kb + (tj + 16 + rc) * 64 + 32 + kg * 8);
        f32x4 s0 = __builtin_amdgcn_mfma_f32_16x16x32_bf16(qlo, b00, z0, 0, 0, 0);
        s0 = __builtin_amdgcn_mfma_f32_16x16x32_bf16(qhi, b01, s0, 0, 0, 0);
        f32x4 s1 = __builtin_amdgcn_mfma_f32_16x16x32_bf16(qlo, b10, z0, 0, 0, 0);
        s1 = __builtin_amdgcn_mfma_f32_16x16x32_bf16(qhi, b11, s1, 0, 0, 0);
        #pragma unroll
        for (int r = 0; r < 4; ++r) {
            int j0 = tj + rc;
            int dsig0 = q0 + r - j0;
            int dd0 = dsig0 < 0 ? -dsig0 : dsig0;
            float e0 = __expf(s0[r] * cfl[dd0]);
            za[r] += e0;
            float em0 = dsig0 >= 0 ? e0 : 0.f;
            zc[r] += em0;
            plds[w][kg * 4 + r][rc] = f2bf(em0);

            int dsig1 = dsig0 - 16;
            int dd1 = dsig1 < 0 ? -dsig1 : dsig1;
            float e1 = __expf(s1[r] * cfl[dd1]);
            za[r] += e1;
            float em1 = dsig1 >= 0 ? e1 : 0.f;
            zc[r] += em1;
            plds[w][kg * 4 + r][16 + rc] = f2bf(em1);
        }
        short8 pf = *(const short8*)(&plds[w][rc][kg * 8]);
        short8 v0 = *(const short8*)(vb + (0 * 16 + rc) * T_ + tj + kg * 8);
        short8 v1 = *(const short8*)(vb + (1 * 16 + rc) * T_ + tj + kg * 8);
        short8 v2 = *(const short8*)(vb + (2 * 16 + rc) * T_ + tj + kg * 8);
        short8 v3 = *(const short8*)(vb + (3 * 16 + rc) * T_ + tj + kg * 8);
        acc[0] = __builtin_amdgcn_mfma_f32_16x16x32_bf16(pf, v0, acc[0], 0, 0, 0);
        acc[1] = __builtin_amdgcn_mfma_f32_16x16x32_bf16(pf, v1, acc[1], 0, 0, 0);
        acc[2] = __builtin_amdgcn_mfma_f32_16x16x32_bf16(pf, v2, acc[2], 0, 0, 0);
        acc[3] = __builtin_amdgcn_mfma_f32_16x16x32_bf16(pf, v3, acc[3], 0, 0, 0);
    }

    for (int jb = nPV; jb < 64; ++jb) {
        int tj = jb * 32;
        short8 b00 = *(const short8*)(kb + (tj + rc) * 64 + kg * 8);
        short8 b01 = *(const short8*)(kb + (tj + rc) * 64 + 32 + kg * 8);
        short8 b10 = *(const short8*)(kb + (tj + 16 + rc) * 64 + kg * 8);
        short8 b11 = *(const short8*)(kb + (tj + 16 + rc) * 64 + 32 + kg * 8);
        f32x4 s0 = __builtin_amdgcn_mfma_f32_16x16x32_bf16(qlo, b00, z0, 0, 0, 0);
        s0 = __builtin_amdgcn_mfma_f32_16x16x32_bf16(qhi, b01, s0, 0, 0, 0);
        f32x4 s1 = __builtin_amdgcn_mfma_f32_16x16x32_bf16(qlo, b10, z0, 0, 0, 0);
        s1 = __builtin_amdgcn_mfma_f32_16x16x32_bf16(qhi, b11, s1, 0, 0, 0);
        #pragma unroll
        for (int r = 0; r < 4; ++r) {
            int dd0 = tj + rc - q0 - r;
            float e0 = __expf(s0[r] * cfl[dd0]);
            int dd1 = dd0 + 16;
            float e1 = __expf(s1[r] * cfl[dd1]);
            za[r] += e0 + e1;
        }
    }

    #pragma unroll
    for (int r = 0; r < 4; ++r) {
        #pragma unroll
        for (int m = 1; m <= 8; m <<= 1) {
            za[r] += __shfl_xor(za[r], m);
            zc[r] += __shfl_xor(zc[r], m);
        }
    }
    float inv[4];
    #pragma unroll
    for (int r = 0; r < 4; ++r) inv[r] = 1.f / (zc[r] + 1e-8f * za[r]);

    #pragma unroll
    for (int dt = 0; dt < 4; ++dt) {
        #pragma unroll
        for (int r = 0; r < 4; ++r) {
            int t = qbase + kg * 4 + r;
            yb[(((size_t)b * T_ + t) * H_ + h) * 64 + dt * 16 + rc] = f2bf(acc[dt][r] * inv[r]);
        }
    }
}

extern "C" void kernel_launch(void* const* d_in, const int* in_sizes, int n_in,
                              void* d_out, int out_size, void* d_ws, size_t ws_size,
                              hipStream_t stream) {
    const float* x    = (const float*)d_in[0];
    const float* cosb = (const float*)d_in[1];
    const float* sinb = (const float*)d_in[2];
    const float* Wq   = (const float*)d_in[3];
    const float* Wk   = (const float*)d_in[4];
    const float* Wv   = (const float*)d_in[5];
    const float* Wo   = (const float*)d_in[6];
    const float* beta = (const float*)d_in[7];
    float* out = (float*)d_out;

    char* ws = (char*)d_ws;
    float*          qraw = (float*)(ws + 0);            // 12.58 MB, dead after rope_q
    unsigned short* yb   = (unsigned short*)(ws + 0);   // aliases qraw (safe: written after)
    float*          kraw = (float*)(ws + 12582912);
    unsigned short* qbf  = (unsigned short*)(ws + 25165824);
    unsigned short* kbf  = (unsigned short*)(ws + 31457280);
    unsigned short* vt   = (unsigned short*)(ws + 37748736);
    unsigned short* xb   = (unsigned short*)(ws + 44040192);
    unsigned short* wqb  = (unsigned short*)(ws + 50331648);
    unsigned short* wkb  = (unsigned short*)(ws + 51511296);
    unsigned short* wvb  = (unsigned short*)(ws + 52690944);
    unsigned short* wob  = (unsigned short*)(ws + 53870592);
    float*          coh  = (float*)(ws + 55050240);

    coh_kernel<<<T_ / 256, 256, 0, stream>>>(coh);

    int nx4 = (B_ * T_ * C_) / 4;
    tobf16_kernel<<<nx4 / 256, 256, 0, stream>>>(x, xb, nx4);
    int nw4 = (C_ * C_) / 4;
    tobf16_kernel<<<nw4 / 256, 256, 0, stream>>>(Wq, wqb, nw4);
    tobf16_kernel<<<nw4 / 256, 256, 0, stream>>>(Wk, wkb, nw4);
    tobf16_kernel<<<nw4 / 256, 256, 0, stream>>>(Wv, wvb, nw4);
    tobf16_kernel<<<nw4 / 256, 256, 0, stream>>>(Wo, wob, nw4);

    dim3 gg(64, 48);
    gemm_nt_kernel<<<gg, 256, 0, stream>>>(xb, wqb, qraw, 4096, 768, 768);
    gemm_nt_kernel<<<gg, 256, 0, stream>>>(xb, wkb, kraw, 4096, 768, 768);
    gemm_nt_vt_kernel<<<gg, 256, 0, stream>>>(xb, wvb, vt, 4096, 768, 768);

    rope_rms_t_kernel<<<(B_ * T_ * H_) / 4, 256, 0, stream>>>(qraw, cosb, sinb, qbf, 0.125f);
    rope_rms_t_kernel<<<(B_ * T_ * H_) / 4, 256, 0, stream>>>(kraw, cosb, sinb, kbf, 1.0f);

    attn_flash_kernel<<<B_ * H_ * (T_ / 64), 256, 0, stream>>>(qbf, kbf, vt, coh, beta, yb);

    gemm_nt_kernel<<<gg, 256, 0, stream>>>(yb, wob, out, 4096, 768, 768);
}

// Round 3
// 261.323 us; speedup vs baseline: 8.0367x; 1.9130x over previous
//
#include <hip/hip_runtime.h>
#include <hip/hip_bf16.h>
#include <math.h>

#define B_ 2
#define T_ 2048
#define C_ 768
#define H_ 12
#define D_ 64

typedef __attribute__((ext_vector_type(8))) short short8;
typedef __attribute__((ext_vector_type(4))) float f32x4;

__device__ inline unsigned short f2bf(float f) {
    unsigned int x = __float_as_uint(f);
    unsigned int r = x + 0x7FFFu + ((x >> 16) & 1u);
    return (unsigned short)(r >> 16);
}

__device__ __forceinline__ void gll16(const void* g, void* l) {
    __builtin_amdgcn_global_load_lds(
        (const __attribute__((address_space(1))) unsigned int*)g,
        (__attribute__((address_space(3))) unsigned int*)l, 16, 0, 0);
}

__global__ void coh_kernel(float* __restrict__ coh) {
    int dd = blockIdx.x * blockDim.x + threadIdx.x;
    if (dd >= T_) return;
    float s = 0.f;
    for (int m = 0; m < 32; ++m) {
        float theta = powf(10000.f, -(float)m / 32.f);
        s += cosf((float)dd * theta);
    }
    coh[dd] = s * (1.f / 32.f);
}

__global__ void tobf16_kernel(const float* __restrict__ src,
                              unsigned short* __restrict__ dst, int n4) {
    int i = blockIdx.x * blockDim.x + threadIdx.x;
    if (i >= n4) return;
    float4 v = ((const float4*)src)[i];
    ushort4 o;
    o.x = f2bf(v.x); o.y = f2bf(v.y); o.z = f2bf(v.z); o.w = f2bf(v.w);
    ((ushort4*)dst)[i] = o;
}

// Fused QKV GEMM: A = xb (4096 x 768 bf16), B = wqkv (2304 x 768 bf16, rows = N).
// 128x128 tile, 4 waves, each wave owns a 64x64 quadrant (= one full head).
// Epilogue: heads 0-11 -> Q (rope+rms, scale 1/8), 12-23 -> K (rope+rms), 24-35 -> V (transpose).
__global__ __launch_bounds__(256) void gemm_qkv_kernel(const unsigned short* __restrict__ xb,
                                                       const unsigned short* __restrict__ wqkv,
                                                       const float* __restrict__ cosb,
                                                       const float* __restrict__ sinb,
                                                       unsigned short* __restrict__ qbf,
                                                       unsigned short* __restrict__ kbf,
                                                       unsigned short* __restrict__ vt) {
    __shared__ unsigned short lA[128][32];
    __shared__ unsigned short lB[128][32];
    __shared__ unsigned short tr[4][64][72];

    int bm = blockIdx.x, tn = blockIdx.y;
    int tid = threadIdx.x;
    int w = tid >> 6, lane = tid & 63;
    int rc = lane & 15, kg = lane >> 4;
    int wr = w >> 1, wc = w & 1;

    const unsigned short* ga = xb + (size_t)(bm * 128 + w * 32 + (lane >> 2)) * 768 + (lane & 3) * 8;
    const unsigned short* gb = wqkv + (size_t)(tn * 128 + w * 32 + (lane >> 2)) * 768 + (lane & 3) * 8;
    unsigned short* la0 = &lA[w * 32][0];
    unsigned short* la1 = &lA[w * 32 + 16][0];
    unsigned short* lb0 = &lB[w * 32][0];
    unsigned short* lb1 = &lB[w * 32 + 16][0];

    f32x4 acc[4][4];
    #pragma unroll
    for (int i = 0; i < 4; ++i)
        #pragma unroll
        for (int j = 0; j < 4; ++j) acc[i][j] = (f32x4){0.f, 0.f, 0.f, 0.f};

    for (int k0 = 0; k0 < 768; k0 += 32) {
        gll16(ga + k0, la0);
        gll16(ga + k0 + 16 * 768, la1);
        gll16(gb + k0, lb0);
        gll16(gb + k0 + 16 * 768, lb1);
        __syncthreads();
        short8 aF[4], bF[4];
        #pragma unroll
        for (int ai = 0; ai < 4; ++ai) aF[ai] = *(const short8*)&lA[wr * 64 + ai * 16 + rc][kg * 8];
        #pragma unroll
        for (int bj = 0; bj < 4; ++bj) bF[bj] = *(const short8*)&lB[wc * 64 + bj * 16 + rc][kg * 8];
        #pragma unroll
        for (int ai = 0; ai < 4; ++ai)
            #pragma unroll
            for (int bj = 0; bj < 4; ++bj)
                acc[ai][bj] = __builtin_amdgcn_mfma_f32_16x16x32_bf16(aF[ai], bF[bj], acc[ai][bj], 0, 0, 0);
        __syncthreads();
    }

    int hg = tn * 2 + wc;
    int tensor = hg / 12;
    int h = hg % 12;

    if (tensor < 2) {
        float scale = tensor == 0 ? 0.125f : 1.0f;
        unsigned short* dst = (tensor == 0 ? qbf : kbf);
        #pragma unroll
        for (int ai = 0; ai < 4; ++ai) {
            #pragma unroll
            for (int rr = 0; rr < 4; ++rr) {
                int m = bm * 128 + wr * 64 + ai * 16 + kg * 4 + rr;
                int b = m >> 11, t = m & 2047;
                float c0 = cosb[t * 32 + rc], c1 = cosb[t * 32 + 16 + rc];
                float s0 = sinb[t * 32 + rc], s1 = sinb[t * 32 + 16 + rc];
                float x0 = acc[ai][0][rr], x1 = acc[ai][1][rr];
                float x2 = acc[ai][2][rr], x3 = acc[ai][3][rr];
                float o0 = x0 * c0 + x2 * s0;
                float o1 = x1 * c1 + x3 * s1;
                float o2 = -x0 * s0 + x2 * c0;
                float o3 = -x1 * s1 + x3 * c1;
                float ss = o0 * o0 + o1 * o1 + o2 * o2 + o3 * o3;
                ss += __shfl_xor(ss, 1); ss += __shfl_xor(ss, 2);
                ss += __shfl_xor(ss, 4); ss += __shfl_xor(ss, 8);
                float rn = rsqrtf(ss * (1.f / 64.f) + 1.1920929e-07f) * scale;
                unsigned short* dp = dst + (((size_t)b * H_ + h) * T_ + t) * 64;
                dp[rc]      = f2bf(o0 * rn);
                dp[16 + rc] = f2bf(o1 * rn);
                dp[32 + rc] = f2bf(o2 * rn);
                dp[48 + rc] = f2bf(o3 * rn);
            }
        }
    } else {
        #pragma unroll
        for (int ai = 0; ai < 4; ++ai)
            #pragma unroll
            for (int bj = 0; bj < 4; ++bj)
                #pragma unroll
                for (int rr = 0; rr < 4; ++rr)
                    tr[w][bj * 16 + rc][ai * 16 + kg * 4 + rr] = f2bf(acc[ai][bj][rr]);
    }
    __syncthreads();
    if (tensor == 2) {
        int m0 = bm * 128 + wr * 64;
        int b = m0 >> 11, t0 = m0 & 2047;
        int d = lane;
        unsigned short* gp = vt + (((size_t)b * H_ + h) * 64 + d) * T_ + t0;
        const uint4* src = (const uint4*)&tr[w][d][0];
        #pragma unroll
        for (int i = 0; i < 8; ++i) ((uint4*)gp)[i] = src[i];
    }
}

// Output GEMM: A = yb bf16, B = wob bf16, C = out f32 (4096 x 768)
__global__ __launch_bounds__(256) void gemm_out_kernel(const unsigned short* __restrict__ A,
                                                       const unsigned short* __restrict__ Bw,
                                                       float* __restrict__ C) {
    __shared__ unsigned short lA[128][32];
    __shared__ unsigned short lB[128][32];
    int bm = blockIdx.x, tn = blockIdx.y;
    int tid = threadIdx.x;
    int w = tid >> 6, lane = tid & 63;
    int rc = lane & 15, kg = lane >> 4;
    int wr = w >> 1, wc = w & 1;

    const unsigned short* ga = A + (size_t)(bm * 128 + w * 32 + (lane >> 2)) * 768 + (lane & 3) * 8;
    const unsigned short* gb = Bw + (size_t)(tn * 128 + w * 32 + (lane >> 2)) * 768 + (lane & 3) * 8;
    unsigned short* la0 = &lA[w * 32][0];
    unsigned short* la1 = &lA[w * 32 + 16][0];
    unsigned short* lb0 = &lB[w * 32][0];
    unsigned short* lb1 = &lB[w * 32 + 16][0];

    f32x4 acc[4][4];
    #pragma unroll
    for (int i = 0; i < 4; ++i)
        #pragma unroll
        for (int j = 0; j < 4; ++j) acc[i][j] = (f32x4){0.f, 0.f, 0.f, 0.f};

    for (int k0 = 0; k0 < 768; k0 += 32) {
        gll16(ga + k0, la0);
        gll16(ga + k0 + 16 * 768, la1);
        gll16(gb + k0, lb0);
        gll16(gb + k0 + 16 * 768, lb1);
        __syncthreads();
        short8 aF[4], bF[4];
        #pragma unroll
        for (int ai = 0; ai < 4; ++ai) aF[ai] = *(const short8*)&lA[wr * 64 + ai * 16 + rc][kg * 8];
        #pragma unroll
        for (int bj = 0; bj < 4; ++bj) bF[bj] = *(const short8*)&lB[wc * 64 + bj * 16 + rc][kg * 8];
        #pragma unroll
        for (int ai = 0; ai < 4; ++ai)
            #pragma unroll
            for (int bj = 0; bj < 4; ++bj)
                acc[ai][bj] = __builtin_amdgcn_mfma_f32_16x16x32_bf16(aF[ai], bF[bj], acc[ai][bj], 0, 0, 0);
        __syncthreads();
    }

    #pragma unroll
    for (int ai = 0; ai < 4; ++ai)
        #pragma unroll
        for (int rr = 0; rr < 4; ++rr) {
            int m = bm * 128 + wr * 64 + ai * 16 + kg * 4 + rr;
            #pragma unroll
            for (int bj = 0; bj < 4; ++bj)
                C[(size_t)m * 768 + tn * 128 + wc * 64 + bj * 16 + rc] = acc[ai][bj][rr];
        }
}

// causal-only flash attention, 64-wide j tiles, long-first ordering
__global__ __launch_bounds__(256) void attn_flash_kernel(const unsigned short* __restrict__ qbf,
                                                         const unsigned short* __restrict__ kbf,
                                                         const unsigned short* __restrict__ vt,
                                                         const float* __restrict__ coh,
                                                         const float* __restrict__ beta,
                                                         unsigned short* __restrict__ yb) {
    __shared__ float cfl[T_];
    __shared__ unsigned short plds[4][16][72];
    int bh = blockIdx.x >> 5;
    int b = bh / H_, h = bh % H_;
    int tq = 31 - (blockIdx.x & 31);
    int w = threadIdx.x >> 6, lane = threadIdx.x & 63;
    int rc = lane & 15, kg = lane >> 4;

    float bv = beta[h];
    for (int i = threadIdx.x; i < T_; i += 256) cfl[i] = 1.f + bv * coh[i];
    __syncthreads();

    int qbase = tq * 64 + w * 16;
    const unsigned short* qb = qbf + ((size_t)bh * T_ + qbase) * 64;
    const unsigned short* kb = kbf + (size_t)bh * T_ * 64;
    const unsigned short* vb = vt + (size_t)bh * 64 * T_;

    short8 qlo = *(const short8*)(qb + rc * 64 + kg * 8);
    short8 qhi = *(const short8*)(qb + rc * 64 + 32 + kg * 8);

    f32x4 acc[4];
    float z[4];
    #pragma unroll
    for (int i = 0; i < 4; ++i) { acc[i] = (f32x4){0.f, 0.f, 0.f, 0.f}; z[i] = 0.f; }

    int q0 = qbase + kg * 4;
    int nt = tq + 1;
    const f32x4 z0 = {0.f, 0.f, 0.f, 0.f};

    for (int it = 0; it < nt; ++it) {
        int tj = it * 64;
        bool masked = (it == nt - 1);
        f32x4 s[4];
        #pragma unroll
        for (int js = 0; js < 4; ++js) {
            short8 k0 = *(const short8*)(kb + (size_t)(tj + js * 16 + rc) * 64 + kg * 8);
            short8 k1 = *(const short8*)(kb + (size_t)(tj + js * 16 + rc) * 64 + 32 + kg * 8);
            s[js] = __builtin_amdgcn_mfma_f32_16x16x32_bf16(qlo, k0, z0, 0, 0, 0);
            s[js] = __builtin_amdgcn_mfma_f32_16x16x32_bf16(qhi, k1, s[js], 0, 0, 0);
        }
        #pragma unroll
        for (int js = 0; js < 4; ++js) {
            #pragma unroll
            for (int r = 0; r < 4; ++r) {
                int dsig = q0 + r - (tj + js * 16 + rc);
                float e;
                if (masked) e = (dsig >= 0) ? __expf(s[js][r] * cfl[dsig]) : 0.f;
                else        e = __expf(s[js][r] * cfl[dsig]);
                z[r] += e;
                plds[w][kg * 4 + r][js * 16 + rc] = f2bf(e);
            }
        }
        short8 pf0 = *(const short8*)&plds[w][rc][kg * 8];
        short8 pf1 = *(const short8*)&plds[w][rc][32 + kg * 8];
        #pragma unroll
        for (int ds = 0; ds < 4; ++ds) {
            short8 v0 = *(const short8*)(vb + (size_t)(ds * 16 + rc) * T_ + tj + kg * 8);
            short8 v1 = *(const short8*)(vb + (size_t)(ds * 16 + rc) * T_ + tj + 32 + kg * 8);
            acc[ds] = __builtin_amdgcn_mfma_f32_16x16x32_bf16(pf0, v0, acc[ds], 0, 0, 0);
            acc[ds] = __builtin_amdgcn_mfma_f32_16x16x32_bf16(pf1, v1, acc[ds], 0, 0, 0);
        }
    }

    #pragma unroll
    for (int r = 0; r < 4; ++r) {
        z[r] += __shfl_xor(z[r], 1); z[r] += __shfl_xor(z[r], 2);
        z[r] += __shfl_xor(z[r], 4); z[r] += __shfl_xor(z[r], 8);
    }
    float inv[4];
    #pragma unroll
    for (int r = 0; r < 4; ++r) inv[r] = 1.f / z[r];

    #pragma unroll
    for (int dt = 0; dt < 4; ++dt) {
        #pragma unroll
        for (int r = 0; r < 4; ++r) {
            int t = qbase + kg * 4 + r;
            yb[(((size_t)b * T_ + t) * H_ + h) * 64 + dt * 16 + rc] = f2bf(acc[dt][r] * inv[r]);
        }
    }
}

extern "C" void kernel_launch(void* const* d_in, const int* in_sizes, int n_in,
                              void* d_out, int out_size, void* d_ws, size_t ws_size,
                              hipStream_t stream) {
    const float* x    = (const float*)d_in[0];
    const float* cosb = (const float*)d_in[1];
    const float* sinb = (const float*)d_in[2];
    const float* Wq   = (const float*)d_in[3];
    const float* Wk   = (const float*)d_in[4];
    const float* Wv   = (const float*)d_in[5];
    const float* Wo   = (const float*)d_in[6];
    const float* beta = (const float*)d_in[7];
    float* out = (float*)d_out;

    char* ws = (char*)d_ws;
    unsigned short* xb   = (unsigned short*)(ws + 0);         // 6291456 B
    unsigned short* wqkv = (unsigned short*)(ws + 6291456);   // 3538944 B
    unsigned short* wob  = (unsigned short*)(ws + 9830400);   // 1179648 B
    unsigned short* qbf  = (unsigned short*)(ws + 11010048);  // 6291456 B
    unsigned short* kbf  = (unsigned short*)(ws + 17301504);  // 6291456 B
    unsigned short* vt   = (unsigned short*)(ws + 23592960);  // 6291456 B
    unsigned short* yb   = (unsigned short*)(ws + 29884416);  // 6291456 B
    float*          coh  = (float*)(ws + 36175872);           // 8192 B

    coh_kernel<<<T_ / 256, 256, 0, stream>>>(coh);

    int nx4 = (B_ * T_ * C_) / 4;
    tobf16_kernel<<<nx4 / 256, 256, 0, stream>>>(x, xb, nx4);
    int nw4 = (C_ * C_) / 4;
    tobf16_kernel<<<nw4 / 256, 256, 0, stream>>>(Wq, wqkv, nw4);
    tobf16_kernel<<<nw4 / 256, 256, 0, stream>>>(Wk, wqkv + 589824, nw4);
    tobf16_kernel<<<nw4 / 256, 256, 0, stream>>>(Wv, wqkv + 1179648, nw4);
    tobf16_kernel<<<nw4 / 256, 256, 0, stream>>>(Wo, wob, nw4);

    dim3 gq(32, 18);
    gemm_qkv_kernel<<<gq, 256, 0, stream>>>(xb, wqkv, cosb, sinb, qbf, kbf, vt);

    attn_flash_kernel<<<B_ * H_ * (T_ / 64), 256, 0, stream>>>(qbf, kbf, vt, coh, beta, yb);

    dim3 go(32, 6);
    gemm_out_kernel<<<go, 256, 0, stream>>>(yb, wob, out);
}

// Round 4
// 136.668 us; speedup vs baseline: 15.3670x; 1.9121x over previous
//
#include <hip/hip_runtime.h>
#include <hip/hip_bf16.h>
#include <math.h>

#define B_ 2
#define T_ 2048
#define C_ 768
#define H_ 12
#define D_ 64

typedef __attribute__((ext_vector_type(8))) short short8;
typedef __attribute__((ext_vector_type(4))) float f32x4;

__device__ inline unsigned short f2bf(float f) {
    unsigned int x = __float_as_uint(f);
    unsigned int r = x + 0x7FFFu + ((x >> 16) & 1u);
    return (unsigned short)(r >> 16);
}

__device__ __forceinline__ void gll16(const void* g, void* l) {
    __builtin_amdgcn_global_load_lds(
        (const __attribute__((address_space(1))) unsigned int*)g,
        (__attribute__((address_space(3))) unsigned int*)l, 16, 0, 0);
}

// fused: x->bf16, Wq/Wk/Wv->wqkv bf16, Wo->wob bf16, plus coh table
__global__ __launch_bounds__(256) void convert_all_kernel(const float* __restrict__ x,
                                                          const float* __restrict__ Wq,
                                                          const float* __restrict__ Wk,
                                                          const float* __restrict__ Wv,
                                                          const float* __restrict__ Wo,
                                                          unsigned short* __restrict__ xb,
                                                          unsigned short* __restrict__ wqkv,
                                                          unsigned short* __restrict__ wob,
                                                          float* __restrict__ coh) {
    if (blockIdx.x >= 5376) {
        int dd = (blockIdx.x - 5376) * 256 + threadIdx.x;
        if (dd < T_) {
            float s = 0.f;
            for (int m = 0; m < 32; ++m) {
                float theta = powf(10000.f, -(float)m / 32.f);
                s += cosf((float)dd * theta);
            }
            coh[dd] = s * (1.f / 32.f);
        }
        return;
    }
    int i = blockIdx.x * 256 + threadIdx.x;   // float4 units
    float4 v;
    ushort4* d;
    if (i < 786432) {
        v = ((const float4*)x)[i];
        d = (ushort4*)xb + i;
    } else {
        int wI = i - 786432;
        int widx = wI / 147456;
        int off = wI - widx * 147456;
        const float* W = widx == 0 ? Wq : widx == 1 ? Wk : widx == 2 ? Wv : Wo;
        v = ((const float4*)W)[off];
        unsigned short* base = (widx == 3) ? wob : (wqkv + widx * 589824);
        d = (ushort4*)base + off;
    }
    ushort4 o;
    o.x = f2bf(v.x); o.y = f2bf(v.y); o.z = f2bf(v.z); o.w = f2bf(v.w);
    *d = o;
}

// Fused QKV GEMM (unchanged from round 3)
__global__ __launch_bounds__(256) void gemm_qkv_kernel(const unsigned short* __restrict__ xb,
                                                       const unsigned short* __restrict__ wqkv,
                                                       const float* __restrict__ cosb,
                                                       const float* __restrict__ sinb,
                                                       unsigned short* __restrict__ qbf,
                                                       unsigned short* __restrict__ kbf,
                                                       unsigned short* __restrict__ vt) {
    __shared__ unsigned short lA[128][32];
    __shared__ unsigned short lB[128][32];
    __shared__ unsigned short tr[4][64][72];

    int bm = blockIdx.x, tn = blockIdx.y;
    int tid = threadIdx.x;
    int w = tid >> 6, lane = tid & 63;
    int rc = lane & 15, kg = lane >> 4;
    int wr = w >> 1, wc = w & 1;

    const unsigned short* ga = xb + (size_t)(bm * 128 + w * 32 + (lane >> 2)) * 768 + (lane & 3) * 8;
    const unsigned short* gb = wqkv + (size_t)(tn * 128 + w * 32 + (lane >> 2)) * 768 + (lane & 3) * 8;
    unsigned short* la0 = &lA[w * 32][0];
    unsigned short* la1 = &lA[w * 32 + 16][0];
    unsigned short* lb0 = &lB[w * 32][0];
    unsigned short* lb1 = &lB[w * 32 + 16][0];

    f32x4 acc[4][4];
    #pragma unroll
    for (int i = 0; i < 4; ++i)
        #pragma unroll
        for (int j = 0; j < 4; ++j) acc[i][j] = (f32x4){0.f, 0.f, 0.f, 0.f};

    for (int k0 = 0; k0 < 768; k0 += 32) {
        gll16(ga + k0, la0);
        gll16(ga + k0 + 16 * 768, la1);
        gll16(gb + k0, lb0);
        gll16(gb + k0 + 16 * 768, lb1);
        __syncthreads();
        short8 aF[4], bF[4];
        #pragma unroll
        for (int ai = 0; ai < 4; ++ai) aF[ai] = *(const short8*)&lA[wr * 64 + ai * 16 + rc][kg * 8];
        #pragma unroll
        for (int bj = 0; bj < 4; ++bj) bF[bj] = *(const short8*)&lB[wc * 64 + bj * 16 + rc][kg * 8];
        #pragma unroll
        for (int ai = 0; ai < 4; ++ai)
            #pragma unroll
            for (int bj = 0; bj < 4; ++bj)
                acc[ai][bj] = __builtin_amdgcn_mfma_f32_16x16x32_bf16(aF[ai], bF[bj], acc[ai][bj], 0, 0, 0);
        __syncthreads();
    }

    int hg = tn * 2 + wc;
    int tensor = hg / 12;
    int h = hg % 12;

    if (tensor < 2) {
        float scale = tensor == 0 ? 0.125f : 1.0f;
        unsigned short* dst = (tensor == 0 ? qbf : kbf);
        #pragma unroll
        for (int ai = 0; ai < 4; ++ai) {
            #pragma unroll
            for (int rr = 0; rr < 4; ++rr) {
                int m = bm * 128 + wr * 64 + ai * 16 + kg * 4 + rr;
                int b = m >> 11, t = m & 2047;
                float c0 = cosb[t * 32 + rc], c1 = cosb[t * 32 + 16 + rc];
                float s0 = sinb[t * 32 + rc], s1 = sinb[t * 32 + 16 + rc];
                float x0 = acc[ai][0][rr], x1 = acc[ai][1][rr];
                float x2 = acc[ai][2][rr], x3 = acc[ai][3][rr];
                float o0 = x0 * c0 + x2 * s0;
                float o1 = x1 * c1 + x3 * s1;
                float o2 = -x0 * s0 + x2 * c0;
                float o3 = -x1 * s1 + x3 * c1;
                float ss = o0 * o0 + o1 * o1 + o2 * o2 + o3 * o3;
                ss += __shfl_xor(ss, 1); ss += __shfl_xor(ss, 2);
                ss += __shfl_xor(ss, 4); ss += __shfl_xor(ss, 8);
                float rn = rsqrtf(ss * (1.f / 64.f) + 1.1920929e-07f) * scale;
                unsigned short* dp = dst + (((size_t)b * H_ + h) * T_ + t) * 64;
                dp[rc]      = f2bf(o0 * rn);
                dp[16 + rc] = f2bf(o1 * rn);
                dp[32 + rc] = f2bf(o2 * rn);
                dp[48 + rc] = f2bf(o3 * rn);
            }
        }
    } else {
        #pragma unroll
        for (int ai = 0; ai < 4; ++ai)
            #pragma unroll
            for (int bj = 0; bj < 4; ++bj)
                #pragma unroll
                for (int rr = 0; rr < 4; ++rr)
                    tr[w][bj * 16 + rc][ai * 16 + kg * 4 + rr] = f2bf(acc[ai][bj][rr]);
    }
    __syncthreads();
    if (tensor == 2) {
        int m0 = bm * 128 + wr * 64;
        int b = m0 >> 11, t0 = m0 & 2047;
        int d = lane;
        unsigned short* gp = vt + (((size_t)b * H_ + h) * 64 + d) * T_ + t0;
        const uint4* src = (const uint4*)&tr[w][d][0];
        #pragma unroll
        for (int i = 0; i < 8; ++i) ((uint4*)gp)[i] = src[i];
    }
}

// Output GEMM (unchanged from round 3)
__global__ __launch_bounds__(256) void gemm_out_kernel(const unsigned short* __restrict__ A,
                                                       const unsigned short* __restrict__ Bw,
                                                       float* __restrict__ C) {
    __shared__ unsigned short lA[128][32];
    __shared__ unsigned short lB[128][32];
    int bm = blockIdx.x, tn = blockIdx.y;
    int tid = threadIdx.x;
    int w = tid >> 6, lane = tid & 63;
    int rc = lane & 15, kg = lane >> 4;
    int wr = w >> 1, wc = w & 1;

    const unsigned short* ga = A + (size_t)(bm * 128 + w * 32 + (lane >> 2)) * 768 + (lane & 3) * 8;
    const unsigned short* gb = Bw + (size_t)(tn * 128 + w * 32 + (lane >> 2)) * 768 + (lane & 3) * 8;
    unsigned short* la0 = &lA[w * 32][0];
    unsigned short* la1 = &lA[w * 32 + 16][0];
    unsigned short* lb0 = &lB[w * 32][0];
    unsigned short* lb1 = &lB[w * 32 + 16][0];

    f32x4 acc[4][4];
    #pragma unroll
    for (int i = 0; i < 4; ++i)
        #pragma unroll
        for (int j = 0; j < 4; ++j) acc[i][j] = (f32x4){0.f, 0.f, 0.f, 0.f};

    for (int k0 = 0; k0 < 768; k0 += 32) {
        gll16(ga + k0, la0);
        gll16(ga + k0 + 16 * 768, la1);
        gll16(gb + k0, lb0);
        gll16(gb + k0 + 16 * 768, lb1);
        __syncthreads();
        short8 aF[4], bF[4];
        #pragma unroll
        for (int ai = 0; ai < 4; ++ai) aF[ai] = *(const short8*)&lA[wr * 64 + ai * 16 + rc][kg * 8];
        #pragma unroll
        for (int bj = 0; bj < 4; ++bj) bF[bj] = *(const short8*)&lB[wc * 64 + bj * 16 + rc][kg * 8];
        #pragma unroll
        for (int ai = 0; ai < 4; ++ai)
            #pragma unroll
            for (int bj = 0; bj < 4; ++bj)
                acc[ai][bj] = __builtin_amdgcn_mfma_f32_16x16x32_bf16(aF[ai], bF[bj], acc[ai][bj], 0, 0, 0);
        __syncthreads();
    }

    #pragma unroll
    for (int ai = 0; ai < 4; ++ai)
        #pragma unroll
        for (int rr = 0; rr < 4; ++rr) {
            int m = bm * 128 + wr * 64 + ai * 16 + kg * 4 + rr;
            #pragma unroll
            for (int bj = 0; bj < 4; ++bj)
                C[(size_t)m * 768 + tn * 128 + wc * 64 + bj * 16 + rc] = acc[ai][bj][rr];
        }
}

// Flash attention: LDS-staged K/V^T (double-buffered, swizzled), causal-only.
// Block = (b,h, 64 q-rows), 4 waves x 16 q-rows. XCD-grouped bh mapping.
__global__ __launch_bounds__(256) void attn_flash_kernel(const unsigned short* __restrict__ qbf,
                                                         const unsigned short* __restrict__ kbf,
                                                         const unsigned short* __restrict__ vt,
                                                         const float* __restrict__ coh,
                                                         const float* __restrict__ beta,
                                                         unsigned short* __restrict__ yb) {
    __shared__ unsigned short kT[2][64][64];
    __shared__ unsigned short vT[2][64][64];
    __shared__ unsigned short plds[4][16][72];
    __shared__ float cfl[T_];

    int p = blockIdx.x;
    int xcd = p & 7, kk = p >> 3;
    int bl = kk >> 5, jsl = kk & 31;
    int bh = xcd * 3 + bl;
    int jj = (bl == 0) ? jsl : (bl == 1 ? (31 - jsl) : ((jsl * 5 + 3) & 31));
    int tq = 31 - jj;
    int b = bh / H_, h = bh % H_;

    int tid = threadIdx.x;
    int w = tid >> 6, lane = tid & 63;
    int rc = lane & 15, kg = lane >> 4;

    float bv = beta[h];
    for (int i = tid; i < T_; i += 256)
        cfl[i] = (1.f + bv * coh[i]) * 1.4426950408889634f;   // fold log2e
    __syncthreads();

    int qbase = tq * 64 + w * 16;
    const unsigned short* qb = qbf + ((size_t)bh * T_ + qbase) * 64;
    const unsigned short* kb = kbf + (size_t)bh * T_ * 64;
    const unsigned short* vb = vt + (size_t)bh * 64 * T_;

    short8 qlo = *(const short8*)(qb + rc * 64 + kg * 8);
    short8 qhi = *(const short8*)(qb + rc * 64 + 32 + kg * 8);

    f32x4 acc[4];
    float z[4];
    #pragma unroll
    for (int i = 0; i < 4; ++i) { acc[i] = (f32x4){0.f, 0.f, 0.f, 0.f}; z[i] = 0.f; }

    int q0 = qbase + kg * 4;
    int nt = tq + 1;
    const f32x4 zf = {0.f, 0.f, 0.f, 0.f};

    // staging: linear LDS dest, pre-swizzled global source (group XOR row&7)
    int r0 = w * 16;
    int rloc = lane >> 3;
    int gsw = (lane & 7) ^ rloc;

    auto stage = [&](int buf, int tj) {
        gll16(kb + (size_t)(tj + r0 + rloc) * 64 + gsw * 8,      &kT[buf][r0][0]);
        gll16(kb + (size_t)(tj + r0 + 8 + rloc) * 64 + gsw * 8,  &kT[buf][r0 + 8][0]);
        gll16(vb + (size_t)(r0 + rloc) * T_ + tj + gsw * 8,      &vT[buf][r0][0]);
        gll16(vb + (size_t)(r0 + 8 + rloc) * T_ + tj + gsw * 8,  &vT[buf][r0 + 8][0]);
    };

    int swz = rc & 7;   // read-side swizzle key (row & 7)

    auto compute = [&](int buf, int tj, bool masked) {
        f32x4 s[4];
        #pragma unroll
        for (int js = 0; js < 4; ++js) {
            int R = js * 16 + rc;
            short8 k0 = *(const short8*)&kT[buf][R][(kg ^ swz) * 8];
            short8 k1 = *(const short8*)&kT[buf][R][((4 + kg) ^ swz) * 8];
            s[js] = __builtin_amdgcn_mfma_f32_16x16x32_bf16(qlo, k0, zf, 0, 0, 0);
            s[js] = __builtin_amdgcn_mfma_f32_16x16x32_bf16(qhi, k1, s[js], 0, 0, 0);
        }
        int base = q0 - rc - tj;
        #pragma unroll
        for (int js = 0; js < 4; ++js) {
            #pragma unroll
            for (int r = 0; r < 4; ++r) {
                int dsig = base + r - js * 16;
                int idx = dsig < 0 ? 0 : dsig;
                float e = exp2f(s[js][r] * cfl[idx]);
                if (masked && dsig < 0) e = 0.f;
                z[r] += e;
                plds[w][kg * 4 + r][js * 16 + rc] = f2bf(e);
            }
        }
        short8 pf0 = *(const short8*)&plds[w][rc][kg * 8];
        short8 pf1 = *(const short8*)&plds[w][rc][32 + kg * 8];
        #pragma unroll
        for (int ds = 0; ds < 4; ++ds) {
            int R = ds * 16 + rc;
            short8 v0 = *(const short8*)&vT[buf][R][(kg ^ swz) * 8];
            short8 v1 = *(const short8*)&vT[buf][R][((4 + kg) ^ swz) * 8];
            acc[ds] = __builtin_amdgcn_mfma_f32_16x16x32_bf16(pf0, v0, acc[ds], 0, 0, 0);
            acc[ds] = __builtin_amdgcn_mfma_f32_16x16x32_bf16(pf1, v1, acc[ds], 0, 0, 0);
        }
    };

    stage(0, 0);
    __syncthreads();
    int cur = 0;
    for (int it = 0; it < nt - 1; ++it) {
        stage(cur ^ 1, (it + 1) * 64);   // prefetch next tile (drained by the syncthreads below)
        compute(cur, it * 64, false);
        __syncthreads();
        cur ^= 1;
    }
    compute(cur, (nt - 1) * 64, true);

    #pragma unroll
    for (int r = 0; r < 4; ++r) {
        z[r] += __shfl_xor(z[r], 1); z[r] += __shfl_xor(z[r], 2);
        z[r] += __shfl_xor(z[r], 4); z[r] += __shfl_xor(z[r], 8);
    }
    float inv[4];
    #pragma unroll
    for (int r = 0; r < 4; ++r) inv[r] = 1.f / z[r];

    #pragma unroll
    for (int dt = 0; dt < 4; ++dt) {
        #pragma unroll
        for (int r = 0; r < 4; ++r) {
            int t = qbase + kg * 4 + r;
            yb[(((size_t)b * T_ + t) * H_ + h) * 64 + dt * 16 + rc] = f2bf(acc[dt][r] * inv[r]);
        }
    }
}

extern "C" void kernel_launch(void* const* d_in, const int* in_sizes, int n_in,
                              void* d_out, int out_size, void* d_ws, size_t ws_size,
                              hipStream_t stream) {
    const float* x    = (const float*)d_in[0];
    const float* cosb = (const float*)d_in[1];
    const float* sinb = (const float*)d_in[2];
    const float* Wq   = (const float*)d_in[3];
    const float* Wk   = (const float*)d_in[4];
    const float* Wv   = (const float*)d_in[5];
    const float* Wo   = (const float*)d_in[6];
    const float* beta = (const float*)d_in[7];
    float* out = (float*)d_out;

    char* ws = (char*)d_ws;
    unsigned short* xb   = (unsigned short*)(ws + 0);         // 6291456 B
    unsigned short* wqkv = (unsigned short*)(ws + 6291456);   // 3538944 B
    unsigned short* wob  = (unsigned short*)(ws + 9830400);   // 1179648 B
    unsigned short* qbf  = (unsigned short*)(ws + 11010048);  // 6291456 B
    unsigned short* kbf  = (unsigned short*)(ws + 17301504);  // 6291456 B
    unsigned short* vt   = (unsigned short*)(ws + 23592960);  // 6291456 B
    unsigned short* yb   = (unsigned short*)(ws + 29884416);  // 6291456 B
    float*          coh  = (float*)(ws + 36175872);           // 8192 B

    convert_all_kernel<<<5384, 256, 0, stream>>>(x, Wq, Wk, Wv, Wo, xb, wqkv, wob, coh);

    dim3 gq(32, 18);
    gemm_qkv_kernel<<<gq, 256, 0, stream>>>(xb, wqkv, cosb, sinb, qbf, kbf, vt);

    attn_flash_kernel<<<B_ * H_ * (T_ / 64), 256, 0, stream>>>(qbf, kbf, vt, coh, beta, yb);

    dim3 go(32, 6);
    gemm_out_kernel<<<go, 256, 0, stream>>>(yb, wob, out);
}

// Round 5
// 114.945 us; speedup vs baseline: 18.2711x; 1.1890x over previous
//
#include <hip/hip_runtime.h>
#include <hip/hip_bf16.h>
#include <math.h>

#define B_ 2
#define T_ 2048
#define C_ 768
#define H_ 12
#define D_ 64

typedef __attribute__((ext_vector_type(8))) short short8;
typedef __attribute__((ext_vector_type(4))) float f32x4;
typedef __attribute__((ext_vector_type(16))) float f32x16;

template <bool V> struct BoolC { static constexpr bool value = V; };

__device__ inline unsigned short f2bf(float f) {
    unsigned int x = __float_as_uint(f);
    unsigned int r = x + 0x7FFFu + ((x >> 16) & 1u);
    return (unsigned short)(r >> 16);
}

__device__ __forceinline__ unsigned cvtpk(float lo, float hi) {
    unsigned r;
    asm("v_cvt_pk_bf16_f32 %0, %1, %2" : "=v"(r) : "v"(lo), "v"(hi));
    return r;
}

// swaps: a.lanes[32..63] <-> b.lanes[0..31]
__device__ __forceinline__ void plswap(unsigned& a, unsigned& b) {
    asm volatile("v_permlane32_swap_b32 %0, %1" : "+v"(a), "+v"(b));
}

__device__ __forceinline__ void gll16(const void* g, void* l) {
    __builtin_amdgcn_global_load_lds(
        (const __attribute__((address_space(1))) unsigned int*)g,
        (__attribute__((address_space(3))) unsigned int*)l, 16, 0, 0);
}

// fused: x->bf16, Wq/Wk/Wv->wqkv bf16, Wo->wob bf16, plus coh table
__global__ __launch_bounds__(256) void convert_all_kernel(const float* __restrict__ x,
                                                          const float* __restrict__ Wq,
                                                          const float* __restrict__ Wk,
                                                          const float* __restrict__ Wv,
                                                          const float* __restrict__ Wo,
                                                          unsigned short* __restrict__ xb,
                                                          unsigned short* __restrict__ wqkv,
                                                          unsigned short* __restrict__ wob,
                                                          float* __restrict__ coh) {
    if (blockIdx.x >= 5376) {
        int dd = (blockIdx.x - 5376) * 256 + threadIdx.x;
        if (dd < T_) {
            float s = 0.f;
            for (int m = 0; m < 32; ++m) {
                float theta = powf(10000.f, -(float)m / 32.f);
                s += cosf((float)dd * theta);
            }
            coh[dd] = s * (1.f / 32.f);
        }
        return;
    }
    int i = blockIdx.x * 256 + threadIdx.x;
    float4 v;
    ushort4* d;
    if (i < 786432) {
        v = ((const float4*)x)[i];
        d = (ushort4*)xb + i;
    } else {
        int wI = i - 786432;
        int widx = wI / 147456;
        int off = wI - widx * 147456;
        const float* W = widx == 0 ? Wq : widx == 1 ? Wk : widx == 2 ? Wv : Wo;
        v = ((const float4*)W)[off];
        unsigned short* base = (widx == 3) ? wob : (wqkv + widx * 589824);
        d = (ushort4*)base + off;
    }
    ushort4 o;
    o.x = f2bf(v.x); o.y = f2bf(v.y); o.z = f2bf(v.z); o.w = f2bf(v.w);
    *d = o;
}

// Fused QKV GEMM (unchanged)
__global__ __launch_bounds__(256) void gemm_qkv_kernel(const unsigned short* __restrict__ xb,
                                                       const unsigned short* __restrict__ wqkv,
                                                       const float* __restrict__ cosb,
                                                       const float* __restrict__ sinb,
                                                       unsigned short* __restrict__ qbf,
                                                       unsigned short* __restrict__ kbf,
                                                       unsigned short* __restrict__ vt) {
    __shared__ unsigned short lA[128][32];
    __shared__ unsigned short lB[128][32];
    __shared__ unsigned short tr[4][64][72];

    int bm = blockIdx.x, tn = blockIdx.y;
    int tid = threadIdx.x;
    int w = tid >> 6, lane = tid & 63;
    int rc = lane & 15, kg = lane >> 4;
    int wr = w >> 1, wc = w & 1;

    const unsigned short* ga = xb + (size_t)(bm * 128 + w * 32 + (lane >> 2)) * 768 + (lane & 3) * 8;
    const unsigned short* gb = wqkv + (size_t)(tn * 128 + w * 32 + (lane >> 2)) * 768 + (lane & 3) * 8;
    unsigned short* la0 = &lA[w * 32][0];
    unsigned short* la1 = &lA[w * 32 + 16][0];
    unsigned short* lb0 = &lB[w * 32][0];
    unsigned short* lb1 = &lB[w * 32 + 16][0];

    f32x4 acc[4][4];
    #pragma unroll
    for (int i = 0; i < 4; ++i)
        #pragma unroll
        for (int j = 0; j < 4; ++j) acc[i][j] = (f32x4){0.f, 0.f, 0.f, 0.f};

    for (int k0 = 0; k0 < 768; k0 += 32) {
        gll16(ga + k0, la0);
        gll16(ga + k0 + 16 * 768, la1);
        gll16(gb + k0, lb0);
        gll16(gb + k0 + 16 * 768, lb1);
        __syncthreads();
        short8 aF[4], bF[4];
        #pragma unroll
        for (int ai = 0; ai < 4; ++ai) aF[ai] = *(const short8*)&lA[wr * 64 + ai * 16 + rc][kg * 8];
        #pragma unroll
        for (int bj = 0; bj < 4; ++bj) bF[bj] = *(const short8*)&lB[wc * 64 + bj * 16 + rc][kg * 8];
        #pragma unroll
        for (int ai = 0; ai < 4; ++ai)
            #pragma unroll
            for (int bj = 0; bj < 4; ++bj)
                acc[ai][bj] = __builtin_amdgcn_mfma_f32_16x16x32_bf16(aF[ai], bF[bj], acc[ai][bj], 0, 0, 0);
        __syncthreads();
    }

    int hg = tn * 2 + wc;
    int tensor = hg / 12;
    int h = hg % 12;

    if (tensor < 2) {
        float scale = tensor == 0 ? 0.125f : 1.0f;
        unsigned short* dst = (tensor == 0 ? qbf : kbf);
        #pragma unroll
        for (int ai = 0; ai < 4; ++ai) {
            #pragma unroll
            for (int rr = 0; rr < 4; ++rr) {
                int m = bm * 128 + wr * 64 + ai * 16 + kg * 4 + rr;
                int b = m >> 11, t = m & 2047;
                float c0 = cosb[t * 32 + rc], c1 = cosb[t * 32 + 16 + rc];
                float s0 = sinb[t * 32 + rc], s1 = sinb[t * 32 + 16 + rc];
                float x0 = acc[ai][0][rr], x1 = acc[ai][1][rr];
                float x2 = acc[ai][2][rr], x3 = acc[ai][3][rr];
                float o0 = x0 * c0 + x2 * s0;
                float o1 = x1 * c1 + x3 * s1;
                float o2 = -x0 * s0 + x2 * c0;
                float o3 = -x1 * s1 + x3 * c1;
                float ss = o0 * o0 + o1 * o1 + o2 * o2 + o3 * o3;
                ss += __shfl_xor(ss, 1); ss += __shfl_xor(ss, 2);
                ss += __shfl_xor(ss, 4); ss += __shfl_xor(ss, 8);
                float rn = rsqrtf(ss * (1.f / 64.f) + 1.1920929e-07f) * scale;
                unsigned short* dp = dst + (((size_t)b * H_ + h) * T_ + t) * 64;
                dp[rc]      = f2bf(o0 * rn);
                dp[16 + rc] = f2bf(o1 * rn);
                dp[32 + rc] = f2bf(o2 * rn);
                dp[48 + rc] = f2bf(o3 * rn);
            }
        }
    } else {
        #pragma unroll
        for (int ai = 0; ai < 4; ++ai)
            #pragma unroll
            for (int bj = 0; bj < 4; ++bj)
                #pragma unroll
                for (int rr = 0; rr < 4; ++rr)
                    tr[w][bj * 16 + rc][ai * 16 + kg * 4 + rr] = f2bf(acc[ai][bj][rr]);
    }
    __syncthreads();
    if (tensor == 2) {
        int m0 = bm * 128 + wr * 64;
        int b = m0 >> 11, t0 = m0 & 2047;
        int d = lane;
        unsigned short* gp = vt + (((size_t)b * H_ + h) * 64 + d) * T_ + t0;
        const uint4* src = (const uint4*)&tr[w][d][0];
        #pragma unroll
        for (int i = 0; i < 8; ++i) ((uint4*)gp)[i] = src[i];
    }
}

// Output GEMM (unchanged)
__global__ __launch_bounds__(256) void gemm_out_kernel(const unsigned short* __restrict__ A,
                                                       const unsigned short* __restrict__ Bw,
                                                       float* __restrict__ C) {
    __shared__ unsigned short lA[128][32];
    __shared__ unsigned short lB[128][32];
    int bm = blockIdx.x, tn = blockIdx.y;
    int tid = threadIdx.x;
    int w = tid >> 6, lane = tid & 63;
    int rc = lane & 15, kg = lane >> 4;
    int wr = w >> 1, wc = w & 1;

    const unsigned short* ga = A + (size_t)(bm * 128 + w * 32 + (lane >> 2)) * 768 + (lane & 3) * 8;
    const unsigned short* gb = Bw + (size_t)(tn * 128 + w * 32 + (lane >> 2)) * 768 + (lane & 3) * 8;
    unsigned short* la0 = &lA[w * 32][0];
    unsigned short* la1 = &lA[w * 32 + 16][0];
    unsigned short* lb0 = &lB[w * 32][0];
    unsigned short* lb1 = &lB[w * 32 + 16][0];

    f32x4 acc[4][4];
    #pragma unroll
    for (int i = 0; i < 4; ++i)
        #pragma unroll
        for (int j = 0; j < 4; ++j) acc[i][j] = (f32x4){0.f, 0.f, 0.f, 0.f};

    for (int k0 = 0; k0 < 768; k0 += 32) {
        gll16(ga + k0, la0);
        gll16(ga + k0 + 16 * 768, la1);
        gll16(gb + k0, lb0);
        gll16(gb + k0 + 16 * 768, lb1);
        __syncthreads();
        short8 aF[4], bF[4];
        #pragma unroll
        for (int ai = 0; ai < 4; ++ai) aF[ai] = *(const short8*)&lA[wr * 64 + ai * 16 + rc][kg * 8];
        #pragma unroll
        for (int bj = 0; bj < 4; ++bj) bF[bj] = *(const short8*)&lB[wc * 64 + bj * 16 + rc][kg * 8];
        #pragma unroll
        for (int ai = 0; ai < 4; ++ai)
            #pragma unroll
            for (int bj = 0; bj < 4; ++bj)
                acc[ai][bj] = __builtin_amdgcn_mfma_f32_16x16x32_bf16(aF[ai], bF[bj], acc[ai][bj], 0, 0, 0);
        __syncthreads();
    }

    #pragma unroll
    for (int ai = 0; ai < 4; ++ai)
        #pragma unroll
        for (int rr = 0; rr < 4; ++rr) {
            int m = bm * 128 + wr * 64 + ai * 16 + kg * 4 + rr;
            #pragma unroll
            for (int bj = 0; bj < 4; ++bj)
                C[(size_t)m * 768 + tn * 128 + wc * 64 + bj * 16 + rc] = acc[ai][bj][rr];
        }
}

// Flash attention, 32x32 MFMA, swapped QK^T, in-register softmax (T12).
// Block = (b,h,64 q-rows); 4 waves = 2 q-subs x 2 j-subs. LDS 40960B -> 4 blk/CU.
__global__ __launch_bounds__(256) void attn_flash_kernel(const unsigned short* __restrict__ qbf,
                                                         const unsigned short* __restrict__ kbf,
                                                         const unsigned short* __restrict__ vt,
                                                         const float* __restrict__ coh,
                                                         const float* __restrict__ beta,
                                                         unsigned short* __restrict__ yb) {
    __shared__ unsigned short kT[2][64][64];
    __shared__ unsigned short vT[2][64][64];
    __shared__ float cfl[T_];

    int p = blockIdx.x;
    int xcd = p & 7, kk = p >> 3;
    int bl = kk >> 5, jsl = kk & 31;
    int bh = xcd * 3 + bl;
    int jj = (bl == 0) ? jsl : (bl == 1 ? (31 - jsl) : ((jsl * 5 + 3) & 31));
    int tq = 31 - jj;
    int b = bh / H_, h = bh % H_;

    int tid = threadIdx.x;
    int w = tid >> 6, lane = tid & 63;
    int qs = w >> 1, js = w & 1;
    int ql = lane & 31, hl = lane >> 5;

    float bv = beta[h];
    for (int i = tid; i < T_; i += 256)
        cfl[i] = (1.f + bv * coh[i]) * 1.4426950408889634f;

    int qb = tq * 64;
    const unsigned short* kb = kbf + (size_t)bh * T_ * 64;
    const unsigned short* vb = vt + (size_t)bh * 64 * T_;

    // Q fragments (B-operand): lane: q = qb+qs*32+ql, d = dstep*16 + hl*8 + j
    const unsigned short* qrow = qbf + ((size_t)bh * T_ + qb + qs * 32 + ql) * 64 + hl * 8;
    short8 qf[4];
    #pragma unroll
    for (int d = 0; d < 4; ++d) qf[d] = *(const short8*)(qrow + d * 16);

    f32x16 acc0, acc1;
    #pragma unroll
    for (int i = 0; i < 16; ++i) { acc0[i] = 0.f; acc1[i] = 0.f; }
    float z = 0.f;

    // per-lane LDS byte offsets (XOR-swizzled reads)
    int Rk = js * 32 + ql;
    int kby[4];
    #pragma unroll
    for (int d = 0; d < 4; ++d) kby[d] = Rk * 128 + (((d * 2 + hl) ^ (Rk & 7)) << 4);
    int vby0[2], vby1[2];
    #pragma unroll
    for (int ks = 0; ks < 2; ++ks) {
        int Rv0 = ql, Rv1 = 32 + ql;
        vby0[ks] = Rv0 * 128 + (((js * 4 + ks * 2 + hl) ^ (Rv0 & 7)) << 4);
        vby1[ks] = Rv1 * 128 + (((js * 4 + ks * 2 + hl) ^ (Rv1 & 7)) << 4);
    }
    const char* kbase = (const char*)&kT[0][0][0];
    const char* vbase = (const char*)&vT[0][0][0];

    int rloc = lane >> 3;
    int gsw = ((lane & 7) ^ rloc) * 8;   // element offset, pre-swizzled source
    int r0 = w * 16;

    auto stage = [&](int buf, int tj) {
        gll16(kb + (size_t)(tj + r0 + rloc) * 64 + gsw,      &kT[buf][r0][0]);
        gll16(kb + (size_t)(tj + r0 + 8 + rloc) * 64 + gsw,  &kT[buf][r0 + 8][0]);
        gll16(vb + (size_t)(r0 + rloc) * T_ + tj + gsw,      &vT[buf][r0][0]);
        gll16(vb + (size_t)(r0 + 8 + rloc) * T_ + tj + gsw,  &vT[buf][r0 + 8][0]);
    };

    int qpos = qb + qs * 32 + ql;

    auto body = [&](int buf, int tj, auto maskc) {
        constexpr bool M = decltype(maskc)::value;
        // QK^T: S^T = K . Q^T  (A=K rows=k, B=Q cols=q, contraction=d)
        f32x16 s;
        #pragma unroll
        for (int i = 0; i < 16; ++i) s[i] = 0.f;
        const char* kp = kbase + buf * 8192;
        __builtin_amdgcn_s_setprio(1);
        #pragma unroll
        for (int d = 0; d < 4; ++d) {
            short8 kf = *(const short8*)(kp + kby[d]);
            s = __builtin_amdgcn_mfma_f32_32x32x16_bf16(kf, qf[d], s, 0, 0, 0);
        }
        __builtin_amdgcn_s_setprio(0);
        int base = qpos - tj - js * 32 - 4 * hl;
        float e[16];
        #pragma unroll
        for (int r = 0; r < 16; ++r) {
            int dd = base - ((r & 3) + 8 * (r >> 2));
            if constexpr (M) {
                float ex = __builtin_amdgcn_exp2f(s[r] * cfl[dd < 0 ? 0 : dd]);
                e[r] = dd >= 0 ? ex : 0.f;
            } else {
                e[r] = __builtin_amdgcn_exp2f(s[r] * cfl[dd]);
            }
            z += e[r];
        }
        // pack P^T fragments: 8 cvt_pk + 4 permlane32_swap (T12)
        unsigned A0 = cvtpk(e[0], e[1]),  B0 = cvtpk(e[2], e[3]);
        unsigned C0 = cvtpk(e[4], e[5]),  D0 = cvtpk(e[6], e[7]);
        unsigned E0 = cvtpk(e[8], e[9]),  F0 = cvtpk(e[10], e[11]);
        unsigned G0 = cvtpk(e[12], e[13]), H0 = cvtpk(e[14], e[15]);
        plswap(A0, C0); plswap(B0, D0); plswap(E0, G0); plswap(F0, H0);
        union U { unsigned u[4]; short8 s8; };
        U p0, p1;
        p0.u[0] = A0; p0.u[1] = B0; p0.u[2] = C0; p0.u[3] = D0;
        p1.u[0] = E0; p1.u[1] = F0; p1.u[2] = G0; p1.u[3] = H0;
        // PV: O^T += V^T . P^T  (A=V^T rows=d, B=P^T cols=q, contraction=k)
        const char* vp = vbase + buf * 8192;
        short8 v00 = *(const short8*)(vp + vby0[0]);
        short8 v01 = *(const short8*)(vp + vby0[1]);
        short8 v10 = *(const short8*)(vp + vby1[0]);
        short8 v11 = *(const short8*)(vp + vby1[1]);
        __builtin_amdgcn_s_setprio(1);
        acc0 = __builtin_amdgcn_mfma_f32_32x32x16_bf16(v00, p0.s8, acc0, 0, 0, 0);
        acc0 = __builtin_amdgcn_mfma_f32_32x32x16_bf16(v01, p1.s8, acc0, 0, 0, 0);
        acc1 = __builtin_amdgcn_mfma_f32_32x32x16_bf16(v10, p0.s8, acc1, 0, 0, 0);
        acc1 = __builtin_amdgcn_mfma_f32_32x32x16_bf16(v11, p1.s8, acc1, 0, 0, 0);
        __builtin_amdgcn_s_setprio(0);
    };

    int nt = tq + 1;
    stage(0, 0);
    __syncthreads();
    int cur = 0;
    for (int it = 0; it < nt - 1; ++it) {
        stage(cur ^ 1, (it + 1) * 64);
        body(cur, it * 64, BoolC<false>{});
        __syncthreads();
        cur ^= 1;
    }
    // diagonal tile: qs>js full, qs==js triangular, qs<js all-masked (skip)
    if (qs > js)      body(cur, (nt - 1) * 64, BoolC<false>{});
    else if (qs == js) body(cur, (nt - 1) * 64, BoolC<true>{});
    __syncthreads();

    // cross-half z, then cross-wave (js pair) O/z reduction via reused LDS
    z += __shfl_xor(z, 32);
    float* osc = (float*)&kT[0][0][0];        // 16KB scratch (2 x 8KB)
    float* zbuf = (float*)&vT[0][0][0];
    if (js == 0) {
        float* o = osc + qs * 2048;
        #pragma unroll
        for (int r = 0; r < 16; ++r) {
            o[r * 64 + lane] = acc0[r];
            o[(16 + r) * 64 + lane] = acc1[r];
        }
        if (lane < 32) zbuf[qs * 32 + ql] = z;
    }
    __syncthreads();
    if (js == 1) {
        float zt = z + zbuf[qs * 32 + ql];
        float invz = 1.f / zt;
        const float* o = osc + qs * 2048;
        #pragma unroll
        for (int r = 0; r < 16; ++r) {
            acc0[r] = (acc0[r] + o[r * 64 + lane]) * invz;
            acc1[r] = (acc1[r] + o[(16 + r) * 64 + lane]) * invz;
        }
        int t = qb + qs * 32 + ql;
        unsigned short* yp = yb + (((size_t)b * T_ + t) * H_ + h) * 64;
        #pragma unroll
        for (int g = 0; g < 4; ++g) {
            uint2 st0, st1;
            st0.x = cvtpk(acc0[g * 4 + 0], acc0[g * 4 + 1]);
            st0.y = cvtpk(acc0[g * 4 + 2], acc0[g * 4 + 3]);
            *(uint2*)(yp + g * 8 + 4 * hl) = st0;
            st1.x = cvtpk(acc1[g * 4 + 0], acc1[g * 4 + 1]);
            st1.y = cvtpk(acc1[g * 4 + 2], acc1[g * 4 + 3]);
            *(uint2*)(yp + 32 + g * 8 + 4 * hl) = st1;
        }
    }
}

extern "C" void kernel_launch(void* const* d_in, const int* in_sizes, int n_in,
                              void* d_out, int out_size, void* d_ws, size_t ws_size,
                              hipStream_t stream) {
    const float* x    = (const float*)d_in[0];
    const float* cosb = (const float*)d_in[1];
    const float* sinb = (const float*)d_in[2];
    const float* Wq   = (const float*)d_in[3];
    const float* Wk   = (const float*)d_in[4];
    const float* Wv   = (const float*)d_in[5];
    const float* Wo   = (const float*)d_in[6];
    const float* beta = (const float*)d_in[7];
    float* out = (float*)d_out;

    char* ws = (char*)d_ws;
    unsigned short* xb   = (unsigned short*)(ws + 0);
    unsigned short* wqkv = (unsigned short*)(ws + 6291456);
    unsigned short* wob  = (unsigned short*)(ws + 9830400);
    unsigned short* qbf  = (unsigned short*)(ws + 11010048);
    unsigned short* kbf  = (unsigned short*)(ws + 17301504);
    unsigned short* vt   = (unsigned short*)(ws + 23592960);
    unsigned short* yb   = (unsigned short*)(ws + 29884416);
    float*          coh  = (float*)(ws + 36175872);

    convert_all_kernel<<<5384, 256, 0, stream>>>(x, Wq, Wk, Wv, Wo, xb, wqkv, wob, coh);

    dim3 gq(32, 18);
    gemm_qkv_kernel<<<gq, 256, 0, stream>>>(xb, wqkv, cosb, sinb, qbf, kbf, vt);

    attn_flash_kernel<<<B_ * H_ * (T_ / 64), 256, 0, stream>>>(qbf, kbf, vt, coh, beta, yb);

    dim3 go(32, 6);
    gemm_out_kernel<<<go, 256, 0, stream>>>(yb, wob, out);
}

// Round 6
// 106.388 us; speedup vs baseline: 19.7408x; 1.0804x over previous
//
#include <hip/hip_runtime.h>
#include <hip/hip_bf16.h>
#include <math.h>

#define B_ 2
#define T_ 2048
#define C_ 768
#define H_ 12
#define D_ 64

typedef __attribute__((ext_vector_type(8))) short short8;
typedef __attribute__((ext_vector_type(4))) float f32x4;
typedef __attribute__((ext_vector_type(16))) float f32x16;

template <bool V> struct BoolC { static constexpr bool value = V; };

#define SBAR() do { asm volatile("" ::: "memory"); __builtin_amdgcn_s_barrier(); asm volatile("" ::: "memory"); } while (0)
#define WAITVM(N) asm volatile("s_waitcnt vmcnt(" #N ")" ::: "memory")

__device__ inline unsigned short f2bf(float f) {
    unsigned int x = __float_as_uint(f);
    unsigned int r = x + 0x7FFFu + ((x >> 16) & 1u);
    return (unsigned short)(r >> 16);
}

__device__ __forceinline__ unsigned cvtpk(float lo, float hi) {
    unsigned r;
    asm("v_cvt_pk_bf16_f32 %0, %1, %2" : "=v"(r) : "v"(lo), "v"(hi));
    return r;
}

__device__ __forceinline__ void plswap(unsigned& a, unsigned& b) {
    asm volatile("v_permlane32_swap_b32 %0, %1" : "+v"(a), "+v"(b));
}

__device__ __forceinline__ void gll16(const void* g, void* l) {
    __builtin_amdgcn_global_load_lds(
        (const __attribute__((address_space(1))) unsigned int*)g,
        (__attribute__((address_space(3))) unsigned int*)l, 16, 0, 0);
}

// fused: x->bf16, Wq/Wk/Wv->wqkv bf16, Wo->wob bf16, plus coh table
__global__ __launch_bounds__(256) void convert_all_kernel(const float* __restrict__ x,
                                                          const float* __restrict__ Wq,
                                                          const float* __restrict__ Wk,
                                                          const float* __restrict__ Wv,
                                                          const float* __restrict__ Wo,
                                                          unsigned short* __restrict__ xb,
                                                          unsigned short* __restrict__ wqkv,
                                                          unsigned short* __restrict__ wob,
                                                          float* __restrict__ coh) {
    if (blockIdx.x >= 5376) {
        int dd = (blockIdx.x - 5376) * 256 + threadIdx.x;
        if (dd < T_) {
            float s = 0.f;
            for (int m = 0; m < 32; ++m) {
                float theta = powf(10000.f, -(float)m / 32.f);
                s += cosf((float)dd * theta);
            }
            coh[dd] = s * (1.f / 32.f);
        }
        return;
    }
    int i = blockIdx.x * 256 + threadIdx.x;
    float4 v;
    ushort4* d;
    if (i < 786432) {
        v = ((const float4*)x)[i];
        d = (ushort4*)xb + i;
    } else {
        int wI = i - 786432;
        int widx = wI / 147456;
        int off = wI - widx * 147456;
        const float* W = widx == 0 ? Wq : widx == 1 ? Wk : widx == 2 ? Wv : Wo;
        v = ((const float4*)W)[off];
        unsigned short* base = (widx == 3) ? wob : (wqkv + widx * 589824);
        d = (ushort4*)base + off;
    }
    ushort4 o;
    o.x = f2bf(v.x); o.y = f2bf(v.y); o.z = f2bf(v.z); o.w = f2bf(v.w);
    *d = o;
}

union QkvSmem {
    struct { unsigned short A[2][128][32]; unsigned short Bm[2][128][32]; } g;
    unsigned short tr[4][64][72];
};

// Fused QKV GEMM, double-buffered LDS + counted vmcnt pipeline.
__global__ __launch_bounds__(256) void gemm_qkv_kernel(const unsigned short* __restrict__ xb,
                                                       const unsigned short* __restrict__ wqkv,
                                                       const float* __restrict__ cosb,
                                                       const float* __restrict__ sinb,
                                                       unsigned short* __restrict__ qbf,
                                                       unsigned short* __restrict__ kbf,
                                                       unsigned short* __restrict__ vt) {
    __shared__ QkvSmem sm;

    int bm = blockIdx.x, tn = blockIdx.y;
    int tid = threadIdx.x;
    int w = tid >> 6, lane = tid & 63;
    int rc = lane & 15, kg = lane >> 4;
    int wr = w >> 1, wc = w & 1;

    const unsigned short* ga = xb + (size_t)(bm * 128 + w * 32 + (lane >> 2)) * 768 + (lane & 3) * 8;
    const unsigned short* gb = wqkv + (size_t)(tn * 128 + w * 32 + (lane >> 2)) * 768 + (lane & 3) * 8;

    f32x4 acc[4][4];
    #pragma unroll
    for (int i = 0; i < 4; ++i)
        #pragma unroll
        for (int j = 0; j < 4; ++j) acc[i][j] = (f32x4){0.f, 0.f, 0.f, 0.f};

    auto stageg = [&](int buf, int k0) {
        gll16(ga + k0, &sm.g.A[buf][w * 32][0]);
        gll16(ga + k0 + 16 * 768, &sm.g.A[buf][w * 32 + 16][0]);
        gll16(gb + k0, &sm.g.Bm[buf][w * 32][0]);
        gll16(gb + k0 + 16 * 768, &sm.g.Bm[buf][w * 32 + 16][0]);
    };
    auto comp = [&](int buf) {
        short8 aF[4], bF[4];
        #pragma unroll
        for (int ai = 0; ai < 4; ++ai) aF[ai] = *(const short8*)&sm.g.A[buf][wr * 64 + ai * 16 + rc][kg * 8];
        #pragma unroll
        for (int bj = 0; bj < 4; ++bj) bF[bj] = *(const short8*)&sm.g.Bm[buf][wc * 64 + bj * 16 + rc][kg * 8];
        __builtin_amdgcn_s_setprio(1);
        #pragma unroll
        for (int ai = 0; ai < 4; ++ai)
            #pragma unroll
            for (int bj = 0; bj < 4; ++bj)
                acc[ai][bj] = __builtin_amdgcn_mfma_f32_16x16x32_bf16(aF[ai], bF[bj], acc[ai][bj], 0, 0, 0);
        __builtin_amdgcn_s_setprio(0);
    };

    stageg(0, 0);
    __syncthreads();
    for (int kk = 0; kk < 23; ++kk) {
        stageg((kk + 1) & 1, (kk + 1) * 32);
        WAITVM(4);
        SBAR();
        comp(kk & 1);
        SBAR();
    }
    WAITVM(0);
    SBAR();
    comp(1);
    __syncthreads();   // before tr aliases the A/B buffers

    int hg = tn * 2 + wc;
    int tensor = hg / 12;
    int h = hg % 12;

    if (tensor < 2) {
        float scale = tensor == 0 ? 0.125f : 1.0f;
        unsigned short* dst = (tensor == 0 ? qbf : kbf);
        #pragma unroll
        for (int ai = 0; ai < 4; ++ai) {
            #pragma unroll
            for (int rr = 0; rr < 4; ++rr) {
                int m = bm * 128 + wr * 64 + ai * 16 + kg * 4 + rr;
                int b = m >> 11, t = m & 2047;
                float c0 = cosb[t * 32 + rc], c1 = cosb[t * 32 + 16 + rc];
                float s0 = sinb[t * 32 + rc], s1 = sinb[t * 32 + 16 + rc];
                float x0 = acc[ai][0][rr], x1 = acc[ai][1][rr];
                float x2 = acc[ai][2][rr], x3 = acc[ai][3][rr];
                float o0 = x0 * c0 + x2 * s0;
                float o1 = x1 * c1 + x3 * s1;
                float o2 = -x0 * s0 + x2 * c0;
                float o3 = -x1 * s1 + x3 * c1;
                float ss = o0 * o0 + o1 * o1 + o2 * o2 + o3 * o3;
                ss += __shfl_xor(ss, 1); ss += __shfl_xor(ss, 2);
                ss += __shfl_xor(ss, 4); ss += __shfl_xor(ss, 8);
                float rn = rsqrtf(ss * (1.f / 64.f) + 1.1920929e-07f) * scale;
                unsigned short* dp = dst + (((size_t)b * H_ + h) * T_ + t) * 64;
                dp[rc]      = f2bf(o0 * rn);
                dp[16 + rc] = f2bf(o1 * rn);
                dp[32 + rc] = f2bf(o2 * rn);
                dp[48 + rc] = f2bf(o3 * rn);
            }
        }
    } else {
        #pragma unroll
        for (int ai = 0; ai < 4; ++ai)
            #pragma unroll
            for (int bj = 0; bj < 4; ++bj)
                #pragma unroll
                for (int rr = 0; rr < 4; ++rr)
                    sm.tr[w][bj * 16 + rc][ai * 16 + kg * 4 + rr] = f2bf(acc[ai][bj][rr]);
    }
    __syncthreads();
    if (tensor == 2) {
        int m0 = bm * 128 + wr * 64;
        int b = m0 >> 11, t0 = m0 & 2047;
        int d = lane;
        unsigned short* gp = vt + (((size_t)b * H_ + h) * 64 + d) * T_ + t0;
        const uint4* src = (const uint4*)&sm.tr[w][d][0];
        #pragma unroll
        for (int i = 0; i < 8; ++i) ((uint4*)gp)[i] = src[i];
    }
}

// Output GEMM: 128x64 tile, double-buffered, counted vmcnt. Grid (32,12).
__global__ __launch_bounds__(256) void gemm_out_kernel(const unsigned short* __restrict__ A,
                                                       const unsigned short* __restrict__ Bw,
                                                       float* __restrict__ C) {
    __shared__ unsigned short lA[2][128][32];
    __shared__ unsigned short lB[2][64][32];
    int bm = blockIdx.x, tn = blockIdx.y;
    int tid = threadIdx.x;
    int w = tid >> 6, lane = tid & 63;
    int rc = lane & 15, kg = lane >> 4;
    int wr = w >> 1, wc = w & 1;

    const unsigned short* ga = A + (size_t)(bm * 128 + w * 32 + (lane >> 2)) * 768 + (lane & 3) * 8;
    const unsigned short* gbB = Bw + (size_t)(tn * 64 + w * 16 + (lane >> 2)) * 768 + (lane & 3) * 8;

    f32x4 acc[4][2];
    #pragma unroll
    for (int i = 0; i < 4; ++i)
        #pragma unroll
        for (int j = 0; j < 2; ++j) acc[i][j] = (f32x4){0.f, 0.f, 0.f, 0.f};

    auto stageg = [&](int buf, int k0) {
        gll16(ga + k0, &lA[buf][w * 32][0]);
        gll16(ga + k0 + 16 * 768, &lA[buf][w * 32 + 16][0]);
        gll16(gbB + k0, &lB[buf][w * 16][0]);
    };
    auto comp = [&](int buf) {
        short8 aF[4], bF[2];
        #pragma unroll
        for (int ai = 0; ai < 4; ++ai) aF[ai] = *(const short8*)&lA[buf][wr * 64 + ai * 16 + rc][kg * 8];
        #pragma unroll
        for (int bj = 0; bj < 2; ++bj) bF[bj] = *(const short8*)&lB[buf][wc * 32 + bj * 16 + rc][kg * 8];
        __builtin_amdgcn_s_setprio(1);
        #pragma unroll
        for (int ai = 0; ai < 4; ++ai)
            #pragma unroll
            for (int bj = 0; bj < 2; ++bj)
                acc[ai][bj] = __builtin_amdgcn_mfma_f32_16x16x32_bf16(aF[ai], bF[bj], acc[ai][bj], 0, 0, 0);
        __builtin_amdgcn_s_setprio(0);
    };

    stageg(0, 0);
    __syncthreads();
    for (int kk = 0; kk < 23; ++kk) {
        stageg((kk + 1) & 1, (kk + 1) * 32);
        WAITVM(3);
        SBAR();
        comp(kk & 1);
        SBAR();
    }
    WAITVM(0);
    SBAR();
    comp(1);

    #pragma unroll
    for (int ai = 0; ai < 4; ++ai)
        #pragma unroll
        for (int rr = 0; rr < 4; ++rr) {
            int m = bm * 128 + wr * 64 + ai * 16 + kg * 4 + rr;
            #pragma unroll
            for (int bj = 0; bj < 2; ++bj)
                C[(size_t)m * 768 + tn * 64 + wc * 32 + bj * 16 + rc] = acc[ai][bj][rr];
        }
}

// Flash attention, 32x32 MFMA, swapped QK^T, in-register softmax,
// double-buffered K/V^T staging with counted vmcnt across raw barriers.
__global__ __launch_bounds__(256) void attn_flash_kernel(const unsigned short* __restrict__ qbf,
                                                         const unsigned short* __restrict__ kbf,
                                                         const unsigned short* __restrict__ vt,
                                                         const float* __restrict__ coh,
                                                         const float* __restrict__ beta,
                                                         unsigned short* __restrict__ yb) {
    __shared__ unsigned short kT[2][64][64];
    __shared__ unsigned short vT[2][64][64];
    __shared__ float cfl[T_];

    int p = blockIdx.x;
    int xcd = p & 7, kk = p >> 3;
    int bl = kk >> 5, jsl = kk & 31;
    int bh = xcd * 3 + bl;
    int jj = (bl == 0) ? jsl : (bl == 1 ? (31 - jsl) : ((jsl * 5 + 3) & 31));
    int tq = 31 - jj;
    int b = bh / H_, h = bh % H_;

    int tid = threadIdx.x;
    int w = tid >> 6, lane = tid & 63;
    int qs = w >> 1, js = w & 1;
    int ql = lane & 31, hl = lane >> 5;

    float bv = beta[h];
    for (int i = tid; i < T_; i += 256)
        cfl[i] = (1.f + bv * coh[i]) * 1.4426950408889634f;

    int qb = tq * 64;
    const unsigned short* kb = kbf + (size_t)bh * T_ * 64;
    const unsigned short* vb = vt + (size_t)bh * 64 * T_;

    const unsigned short* qrow = qbf + ((size_t)bh * T_ + qb + qs * 32 + ql) * 64 + hl * 8;
    short8 qf[4];
    #pragma unroll
    for (int d = 0; d < 4; ++d) qf[d] = *(const short8*)(qrow + d * 16);

    f32x16 acc0, acc1;
    #pragma unroll
    for (int i = 0; i < 16; ++i) { acc0[i] = 0.f; acc1[i] = 0.f; }
    float z = 0.f;

    int Rk = js * 32 + ql;
    int kby[4];
    #pragma unroll
    for (int d = 0; d < 4; ++d) kby[d] = Rk * 128 + (((d * 2 + hl) ^ (Rk & 7)) << 4);
    int vby0[2], vby1[2];
    #pragma unroll
    for (int ks = 0; ks < 2; ++ks) {
        int Rv0 = ql, Rv1 = 32 + ql;
        vby0[ks] = Rv0 * 128 + (((js * 4 + ks * 2 + hl) ^ (Rv0 & 7)) << 4);
        vby1[ks] = Rv1 * 128 + (((js * 4 + ks * 2 + hl) ^ (Rv1 & 7)) << 4);
    }
    const char* kbase = (const char*)&kT[0][0][0];
    const char* vbase = (const char*)&vT[0][0][0];

    int rloc = lane >> 3;
    int gsw = ((lane & 7) ^ rloc) * 8;
    int r0 = w * 16;

    auto stage = [&](int buf, int tj) {
        gll16(kb + (size_t)(tj + r0 + rloc) * 64 + gsw,      &kT[buf][r0][0]);
        gll16(kb + (size_t)(tj + r0 + 8 + rloc) * 64 + gsw,  &kT[buf][r0 + 8][0]);
        gll16(vb + (size_t)(r0 + rloc) * T_ + tj + gsw,      &vT[buf][r0][0]);
        gll16(vb + (size_t)(r0 + 8 + rloc) * T_ + tj + gsw,  &vT[buf][r0 + 8][0]);
    };

    int qpos = qb + qs * 32 + ql;

    auto body = [&](int buf, int tj, auto maskc) {
        constexpr bool M = decltype(maskc)::value;
        f32x16 s;
        #pragma unroll
        for (int i = 0; i < 16; ++i) s[i] = 0.f;
        const char* kp = kbase + buf * 8192;
        __builtin_amdgcn_s_setprio(1);
        #pragma unroll
        for (int d = 0; d < 4; ++d) {
            short8 kf = *(const short8*)(kp + kby[d]);
            s = __builtin_amdgcn_mfma_f32_32x32x16_bf16(kf, qf[d], s, 0, 0, 0);
        }
        __builtin_amdgcn_s_setprio(0);
        int base = qpos - tj - js * 32 - 4 * hl;
        float e[16];
        #pragma unroll
        for (int r = 0; r < 16; ++r) {
            int dd = base - ((r & 3) + 8 * (r >> 2));
            if constexpr (M) {
                float ex = __builtin_amdgcn_exp2f(s[r] * cfl[dd < 0 ? 0 : dd]);
                e[r] = dd >= 0 ? ex : 0.f;
            } else {
                e[r] = __builtin_amdgcn_exp2f(s[r] * cfl[dd]);
            }
            z += e[r];
        }
        unsigned A0 = cvtpk(e[0], e[1]),  B0 = cvtpk(e[2], e[3]);
        unsigned C0 = cvtpk(e[4], e[5]),  D0 = cvtpk(e[6], e[7]);
        unsigned E0 = cvtpk(e[8], e[9]),  F0 = cvtpk(e[10], e[11]);
        unsigned G0 = cvtpk(e[12], e[13]), H0 = cvtpk(e[14], e[15]);
        plswap(A0, C0); plswap(B0, D0); plswap(E0, G0); plswap(F0, H0);
        union U { unsigned u[4]; short8 s8; };
        U p0, p1;
        p0.u[0] = A0; p0.u[1] = B0; p0.u[2] = C0; p0.u[3] = D0;
        p1.u[0] = E0; p1.u[1] = F0; p1.u[2] = G0; p1.u[3] = H0;
        const char* vp = vbase + buf * 8192;
        short8 v00 = *(const short8*)(vp + vby0[0]);
        short8 v01 = *(const short8*)(vp + vby0[1]);
        short8 v10 = *(const short8*)(vp + vby1[0]);
        short8 v11 = *(const short8*)(vp + vby1[1]);
        __builtin_amdgcn_s_setprio(1);
        acc0 = __builtin_amdgcn_mfma_f32_32x32x16_bf16(v00, p0.s8, acc0, 0, 0, 0);
        acc0 = __builtin_amdgcn_mfma_f32_32x32x16_bf16(v01, p1.s8, acc0, 0, 0, 0);
        acc1 = __builtin_amdgcn_mfma_f32_32x32x16_bf16(v10, p0.s8, acc1, 0, 0, 0);
        acc1 = __builtin_amdgcn_mfma_f32_32x32x16_bf16(v11, p1.s8, acc1, 0, 0, 0);
        __builtin_amdgcn_s_setprio(0);
    };

    int nt = tq + 1;
    stage(0, 0);
    __syncthreads();   // full drain once: buf0 + cfl + qf resolved
    int cur = 0;
    for (int it = 0; it < nt - 1; ++it) {
        stage(cur ^ 1, (it + 1) * 64);
        WAITVM(4);
        SBAR();
        body(cur, it * 64, BoolC<false>{});
        SBAR();
        cur ^= 1;
    }
    WAITVM(0);
    SBAR();
    // diagonal tile: qs>js full, qs==js triangular, qs<js all-masked (skip)
    if (qs > js)      body(cur, (nt - 1) * 64, BoolC<false>{});
    else if (qs == js) body(cur, (nt - 1) * 64, BoolC<true>{});
    __syncthreads();

    z += __shfl_xor(z, 32);
    float* osc = (float*)&kT[0][0][0];
    float* zbuf = (float*)&vT[0][0][0];
    if (js == 0) {
        float* o = osc + qs * 2048;
        #pragma unroll
        for (int r = 0; r < 16; ++r) {
            o[r * 64 + lane] = acc0[r];
            o[(16 + r) * 64 + lane] = acc1[r];
        }
        if (lane < 32) zbuf[qs * 32 + ql] = z;
    }
    __syncthreads();
    if (js == 1) {
        float zt = z + zbuf[qs * 32 + ql];
        float invz = 1.f / zt;
        const float* o = osc + qs * 2048;
        #pragma unroll
        for (int r = 0; r < 16; ++r) {
            acc0[r] = (acc0[r] + o[r * 64 + lane]) * invz;
            acc1[r] = (acc1[r] + o[(16 + r) * 64 + lane]) * invz;
        }
        int t = qb + qs * 32 + ql;
        unsigned short* yp = yb + (((size_t)b * T_ + t) * H_ + h) * 64;
        #pragma unroll
        for (int g = 0; g < 4; ++g) {
            uint2 st0, st1;
            st0.x = cvtpk(acc0[g * 4 + 0], acc0[g * 4 + 1]);
            st0.y = cvtpk(acc0[g * 4 + 2], acc0[g * 4 + 3]);
            *(uint2*)(yp + g * 8 + 4 * hl) = st0;
            st1.x = cvtpk(acc1[g * 4 + 0], acc1[g * 4 + 1]);
            st1.y = cvtpk(acc1[g * 4 + 2], acc1[g * 4 + 3]);
            *(uint2*)(yp + 32 + g * 8 + 4 * hl) = st1;
        }
    }
}

extern "C" void kernel_launch(void* const* d_in, const int* in_sizes, int n_in,
                              void* d_out, int out_size, void* d_ws, size_t ws_size,
                              hipStream_t stream) {
    const float* x    = (const float*)d_in[0];
    const float* cosb = (const float*)d_in[1];
    const float* sinb = (const float*)d_in[2];
    const float* Wq   = (const float*)d_in[3];
    const float* Wk   = (const float*)d_in[4];
    const float* Wv   = (const float*)d_in[5];
    const float* Wo   = (const float*)d_in[6];
    const float* beta = (const float*)d_in[7];
    float* out = (float*)d_out;

    char* ws = (char*)d_ws;
    unsigned short* xb   = (unsigned short*)(ws + 0);
    unsigned short* wqkv = (unsigned short*)(ws + 6291456);
    unsigned short* wob  = (unsigned short*)(ws + 9830400);
    unsigned short* qbf  = (unsigned short*)(ws + 11010048);
    unsigned short* kbf  = (unsigned short*)(ws + 17301504);
    unsigned short* vt   = (unsigned short*)(ws + 23592960);
    unsigned short* yb   = (unsigned short*)(ws + 29884416);
    float*          coh  = (float*)(ws + 36175872);

    convert_all_kernel<<<5384, 256, 0, stream>>>(x, Wq, Wk, Wv, Wo, xb, wqkv, wob, coh);

    dim3 gq(32, 18);
    gemm_qkv_kernel<<<gq, 256, 0, stream>>>(xb, wqkv, cosb, sinb, qbf, kbf, vt);

    attn_flash_kernel<<<B_ * H_ * (T_ / 64), 256, 0, stream>>>(qbf, kbf, vt, coh, beta, yb);

    dim3 go(32, 12);
    gemm_out_kernel<<<go, 256, 0, stream>>>(yb, wob, out);
}

// Round 7
// 98.012 us; speedup vs baseline: 21.4277x; 1.0855x over previous
//
#include <hip/hip_runtime.h>
#include <hip/hip_bf16.h>
#include <math.h>

#define B_ 2
#define T_ 2048
#define C_ 768
#define H_ 12
#define D_ 64

typedef __attribute__((ext_vector_type(8))) short short8;
typedef __attribute__((ext_vector_type(4))) float f32x4;
typedef __attribute__((ext_vector_type(16))) float f32x16;

template <bool V> struct BoolC { static constexpr bool value = V; };

#define SBAR() do { asm volatile("" ::: "memory"); __builtin_amdgcn_s_barrier(); asm volatile("" ::: "memory"); } while (0)
#define WAITVM(N) asm volatile("s_waitcnt vmcnt(" #N ")" ::: "memory")

__device__ inline unsigned short f2bf(float f) {
    unsigned int x = __float_as_uint(f);
    unsigned int r = x + 0x7FFFu + ((x >> 16) & 1u);
    return (unsigned short)(r >> 16);
}

__device__ __forceinline__ unsigned cvtpk(float lo, float hi) {
    unsigned r;
    asm("v_cvt_pk_bf16_f32 %0, %1, %2" : "=v"(r) : "v"(lo), "v"(hi));
    return r;
}

__device__ __forceinline__ void plswap(unsigned& a, unsigned& b) {
    asm volatile("v_permlane32_swap_b32 %0, %1" : "+v"(a), "+v"(b));
}

__device__ __forceinline__ void gll16(const void* g, void* l) {
    __builtin_amdgcn_global_load_lds(
        (const __attribute__((address_space(1))) unsigned int*)g,
        (__attribute__((address_space(3))) unsigned int*)l, 16, 0, 0);
}

// fused: x->bf16, Wq/Wk/Wv->wqkv bf16, Wo->wob bf16, plus coh table
__global__ __launch_bounds__(256) void convert_all_kernel(const float* __restrict__ x,
                                                          const float* __restrict__ Wq,
                                                          const float* __restrict__ Wk,
                                                          const float* __restrict__ Wv,
                                                          const float* __restrict__ Wo,
                                                          unsigned short* __restrict__ xb,
                                                          unsigned short* __restrict__ wqkv,
                                                          unsigned short* __restrict__ wob,
                                                          float* __restrict__ coh) {
    if (blockIdx.x >= 5376) {
        int dd = (blockIdx.x - 5376) * 256 + threadIdx.x;
        if (dd < T_) {
            float s = 0.f;
            for (int m = 0; m < 32; ++m) {
                float theta = powf(10000.f, -(float)m / 32.f);
                s += cosf((float)dd * theta);
            }
            coh[dd] = s * (1.f / 32.f);
        }
        return;
    }
    int i = blockIdx.x * 256 + threadIdx.x;
    float4 v;
    ushort4* d;
    if (i < 786432) {
        v = ((const float4*)x)[i];
        d = (ushort4*)xb + i;
    } else {
        int wI = i - 786432;
        int widx = wI / 147456;
        int off = wI - widx * 147456;
        const float* W = widx == 0 ? Wq : widx == 1 ? Wk : widx == 2 ? Wv : Wo;
        v = ((const float4*)W)[off];
        unsigned short* base = (widx == 3) ? wob : (wqkv + widx * 589824);
        d = (ushort4*)base + off;
    }
    ushort4 o;
    o.x = f2bf(v.x); o.y = f2bf(v.y); o.z = f2bf(v.z); o.w = f2bf(v.w);
    *d = o;
}

union QkvSmem {
    struct { unsigned short A[2][128][32]; unsigned short Bm[2][64][32]; } g;  // 24 KB
    unsigned short tr[64][136];                                               // 17.4 KB
};

// Fused QKV GEMM: 128x64 tile (one head per block), grid (32,36) = 1152 blocks.
// 4 waves, each owns 32 rows x 64 cols. Double-buffered LDS + counted vmcnt.
__global__ __launch_bounds__(256, 4) void gemm_qkv_kernel(const unsigned short* __restrict__ xb,
                                                          const unsigned short* __restrict__ wqkv,
                                                          const float* __restrict__ cosb,
                                                          const float* __restrict__ sinb,
                                                          unsigned short* __restrict__ qbf,
                                                          unsigned short* __restrict__ kbf,
                                                          unsigned short* __restrict__ vt) {
    __shared__ QkvSmem sm;

    int bm = blockIdx.x, tn = blockIdx.y;
    int tid = threadIdx.x;
    int w = tid >> 6, lane = tid & 63;
    int rc = lane & 15, kg = lane >> 4;

    const unsigned short* ga = xb + (size_t)(bm * 128 + w * 32 + (lane >> 2)) * 768 + (lane & 3) * 8;
    const unsigned short* gb = wqkv + (size_t)(tn * 64 + w * 16 + (lane >> 2)) * 768 + (lane & 3) * 8;

    f32x4 acc[2][4];
    #pragma unroll
    for (int i = 0; i < 2; ++i)
        #pragma unroll
        for (int j = 0; j < 4; ++j) acc[i][j] = (f32x4){0.f, 0.f, 0.f, 0.f};

    auto stageg = [&](int buf, int k0) {
        gll16(ga + k0, &sm.g.A[buf][w * 32][0]);
        gll16(ga + k0 + 16 * 768, &sm.g.A[buf][w * 32 + 16][0]);
        gll16(gb + k0, &sm.g.Bm[buf][w * 16][0]);
    };
    auto comp = [&](int buf) {
        short8 aF[2], bF[4];
        #pragma unroll
        for (int ai = 0; ai < 2; ++ai) aF[ai] = *(const short8*)&sm.g.A[buf][w * 32 + ai * 16 + rc][kg * 8];
        #pragma unroll
        for (int bj = 0; bj < 4; ++bj) bF[bj] = *(const short8*)&sm.g.Bm[buf][bj * 16 + rc][kg * 8];
        __builtin_amdgcn_s_setprio(1);
        #pragma unroll
        for (int ai = 0; ai < 2; ++ai)
            #pragma unroll
            for (int bj = 0; bj < 4; ++bj)
                acc[ai][bj] = __builtin_amdgcn_mfma_f32_16x16x32_bf16(aF[ai], bF[bj], acc[ai][bj], 0, 0, 0);
        __builtin_amdgcn_s_setprio(0);
    };

    stageg(0, 0);
    __syncthreads();
    for (int kk = 0; kk < 23; ++kk) {
        stageg((kk + 1) & 1, (kk + 1) * 32);
        WAITVM(3);
        SBAR();
        comp(kk & 1);
        SBAR();
    }
    WAITVM(0);
    SBAR();
    comp(1);
    __syncthreads();   // before tr aliases the A/B buffers

    int tensor = tn / 12;
    int h = tn % 12;

    if (tensor < 2) {
        float scale = tensor == 0 ? 0.125f : 1.0f;
        unsigned short* dst = (tensor == 0 ? qbf : kbf);
        #pragma unroll
        for (int ai = 0; ai < 2; ++ai) {
            #pragma unroll
            for (int rr = 0; rr < 4; ++rr) {
                int m = bm * 128 + w * 32 + ai * 16 + kg * 4 + rr;
                int b = m >> 11, t = m & 2047;
                float c0 = cosb[t * 32 + rc], c1 = cosb[t * 32 + 16 + rc];
                float s0 = sinb[t * 32 + rc], s1 = sinb[t * 32 + 16 + rc];
                float x0 = acc[ai][0][rr], x1 = acc[ai][1][rr];
                float x2 = acc[ai][2][rr], x3 = acc[ai][3][rr];
                float o0 = x0 * c0 + x2 * s0;
                float o1 = x1 * c1 + x3 * s1;
                float o2 = -x0 * s0 + x2 * c0;
                float o3 = -x1 * s1 + x3 * c1;
                float ss = o0 * o0 + o1 * o1 + o2 * o2 + o3 * o3;
                ss += __shfl_xor(ss, 1); ss += __shfl_xor(ss, 2);
                ss += __shfl_xor(ss, 4); ss += __shfl_xor(ss, 8);
                float rn = rsqrtf(ss * (1.f / 64.f) + 1.1920929e-07f) * scale;
                unsigned short* dp = dst + (((size_t)b * H_ + h) * T_ + t) * 64;
                dp[rc]      = f2bf(o0 * rn);
                dp[16 + rc] = f2bf(o1 * rn);
                dp[32 + rc] = f2bf(o2 * rn);
                dp[48 + rc] = f2bf(o3 * rn);
            }
        }
    } else {
        // V: transpose via LDS, write (b,h,d,t) bf16
        #pragma unroll
        for (int ai = 0; ai < 2; ++ai)
            #pragma unroll
            for (int bj = 0; bj < 4; ++bj)
                #pragma unroll
                for (int rr = 0; rr < 4; ++rr)
                    sm.tr[bj * 16 + rc][w * 32 + ai * 16 + kg * 4 + rr] = f2bf(acc[ai][bj][rr]);
        __syncthreads();
        int m0 = bm * 128;
        int b = m0 >> 11, t0 = m0 & 2047;
        int d = w * 16 + (lane >> 2);
        int tl = (lane & 3) * 32;
        unsigned short* gp = vt + (((size_t)b * H_ + h) * 64 + d) * T_ + t0 + tl;
        #pragma unroll
        for (int i = 0; i < 4; ++i)
            *(uint4*)(gp + i * 8) = *(const uint4*)&sm.tr[d][tl + i * 8];
    }
}

// Output GEMM: 64x64 tile, grid (64,12) = 768 blocks, double-buffered.
__global__ __launch_bounds__(256, 4) void gemm_out_kernel(const unsigned short* __restrict__ A,
                                                          const unsigned short* __restrict__ Bw,
                                                          float* __restrict__ C) {
    __shared__ unsigned short lA[2][64][32];
    __shared__ unsigned short lB[2][64][32];
    int bm = blockIdx.x, tn = blockIdx.y;
    int tid = threadIdx.x;
    int w = tid >> 6, lane = tid & 63;
    int rc = lane & 15, kg = lane >> 4;
    int wr = w >> 1, wc = w & 1;

    const unsigned short* ga = A + (size_t)(bm * 64 + w * 16 + (lane >> 2)) * 768 + (lane & 3) * 8;
    const unsigned short* gbB = Bw + (size_t)(tn * 64 + w * 16 + (lane >> 2)) * 768 + (lane & 3) * 8;

    f32x4 acc[2][2];
    #pragma unroll
    for (int i = 0; i < 2; ++i)
        #pragma unroll
        for (int j = 0; j < 2; ++j) acc[i][j] = (f32x4){0.f, 0.f, 0.f, 0.f};

    auto stageg = [&](int buf, int k0) {
        gll16(ga + k0, &lA[buf][w * 16][0]);
        gll16(gbB + k0, &lB[buf][w * 16][0]);
    };
    auto comp = [&](int buf) {
        short8 aF[2], bF[2];
        #pragma unroll
        for (int ai = 0; ai < 2; ++ai) aF[ai] = *(const short8*)&lA[buf][wr * 32 + ai * 16 + rc][kg * 8];
        #pragma unroll
        for (int bj = 0; bj < 2; ++bj) bF[bj] = *(const short8*)&lB[buf][wc * 32 + bj * 16 + rc][kg * 8];
        __builtin_amdgcn_s_setprio(1);
        #pragma unroll
        for (int ai = 0; ai < 2; ++ai)
            #pragma unroll
            for (int bj = 0; bj < 2; ++bj)
                acc[ai][bj] = __builtin_amdgcn_mfma_f32_16x16x32_bf16(aF[ai], bF[bj], acc[ai][bj], 0, 0, 0);
        __builtin_amdgcn_s_setprio(0);
    };

    stageg(0, 0);
    __syncthreads();
    for (int kk = 0; kk < 23; ++kk) {
        stageg((kk + 1) & 1, (kk + 1) * 32);
        WAITVM(2);
        SBAR();
        comp(kk & 1);
        SBAR();
    }
    WAITVM(0);
    SBAR();
    comp(1);

    #pragma unroll
    for (int ai = 0; ai < 2; ++ai)
        #pragma unroll
        for (int rr = 0; rr < 4; ++rr) {
            int m = bm * 64 + wr * 32 + ai * 16 + kg * 4 + rr;
            #pragma unroll
            for (int bj = 0; bj < 2; ++bj)
                C[(size_t)m * 768 + tn * 64 + wc * 32 + bj * 16 + rc] = acc[ai][bj][rr];
        }
}

// Flash attention, 32x32 MFMA, swapped QK^T, in-register softmax,
// double-buffered K/V^T staging with counted vmcnt across raw barriers.
// __launch_bounds__(256,4): cap VGPR <=128 to unlock 4 blocks/CU.
__global__ __launch_bounds__(256, 4) void attn_flash_kernel(const unsigned short* __restrict__ qbf,
                                                            const unsigned short* __restrict__ kbf,
                                                            const unsigned short* __restrict__ vt,
                                                            const float* __restrict__ coh,
                                                            const float* __restrict__ beta,
                                                            unsigned short* __restrict__ yb) {
    __shared__ unsigned short kT[2][64][64];
    __shared__ unsigned short vT[2][64][64];
    __shared__ float cfl[T_];

    int p = blockIdx.x;
    int xcd = p & 7, kk = p >> 3;
    int bl = kk >> 5, jsl = kk & 31;
    int bh = xcd * 3 + bl;
    int jj = (bl == 0) ? jsl : (bl == 1 ? (31 - jsl) : ((jsl * 5 + 3) & 31));
    int tq = 31 - jj;
    int b = bh / H_, h = bh % H_;

    int tid = threadIdx.x;
    int w = tid >> 6, lane = tid & 63;
    int qs = w >> 1, js = w & 1;
    int ql = lane & 31, hl = lane >> 5;

    float bv = beta[h];
    for (int i = tid; i < T_; i += 256)
        cfl[i] = (1.f + bv * coh[i]) * 1.4426950408889634f;

    int qb = tq * 64;
    const unsigned short* kb = kbf + (size_t)bh * T_ * 64;
    const unsigned short* vb = vt + (size_t)bh * 64 * T_;

    const unsigned short* qrow = qbf + ((size_t)bh * T_ + qb + qs * 32 + ql) * 64 + hl * 8;
    short8 qf[4];
    #pragma unroll
    for (int d = 0; d < 4; ++d) qf[d] = *(const short8*)(qrow + d * 16);

    f32x16 acc0, acc1;
    #pragma unroll
    for (int i = 0; i < 16; ++i) { acc0[i] = 0.f; acc1[i] = 0.f; }
    float z = 0.f;

    int Rk = js * 32 + ql;
    int kby[4];
    #pragma unroll
    for (int d = 0; d < 4; ++d) kby[d] = Rk * 128 + (((d * 2 + hl) ^ (Rk & 7)) << 4);
    int vby0[2], vby1[2];
    #pragma unroll
    for (int ks = 0; ks < 2; ++ks) {
        int Rv0 = ql, Rv1 = 32 + ql;
        vby0[ks] = Rv0 * 128 + (((js * 4 + ks * 2 + hl) ^ (Rv0 & 7)) << 4);
        vby1[ks] = Rv1 * 128 + (((js * 4 + ks * 2 + hl) ^ (Rv1 & 7)) << 4);
    }
    const char* kbase = (const char*)&kT[0][0][0];
    const char* vbase = (const char*)&vT[0][0][0];

    int rloc = lane >> 3;
    int gsw = ((lane & 7) ^ rloc) * 8;
    int r0 = w * 16;

    auto stage = [&](int buf, int tj) {
        gll16(kb + (size_t)(tj + r0 + rloc) * 64 + gsw,      &kT[buf][r0][0]);
        gll16(kb + (size_t)(tj + r0 + 8 + rloc) * 64 + gsw,  &kT[buf][r0 + 8][0]);
        gll16(vb + (size_t)(r0 + rloc) * T_ + tj + gsw,      &vT[buf][r0][0]);
        gll16(vb + (size_t)(r0 + 8 + rloc) * T_ + tj + gsw,  &vT[buf][r0 + 8][0]);
    };

    int qpos = qb + qs * 32 + ql;

    auto body = [&](int buf, int tj, auto maskc) {
        constexpr bool M = decltype(maskc)::value;
        f32x16 s;
        #pragma unroll
        for (int i = 0; i < 16; ++i) s[i] = 0.f;
        const char* kp = kbase + buf * 8192;
        __builtin_amdgcn_s_setprio(1);
        #pragma unroll
        for (int d = 0; d < 4; ++d) {
            short8 kf = *(const short8*)(kp + kby[d]);
            s = __builtin_amdgcn_mfma_f32_32x32x16_bf16(kf, qf[d], s, 0, 0, 0);
        }
        __builtin_amdgcn_s_setprio(0);
        int base = qpos - tj - js * 32 - 4 * hl;
        float e[16];
        #pragma unroll
        for (int r = 0; r < 16; ++r) {
            int dd = base - ((r & 3) + 8 * (r >> 2));
            if constexpr (M) {
                float ex = __builtin_amdgcn_exp2f(s[r] * cfl[dd < 0 ? 0 : dd]);
                e[r] = dd >= 0 ? ex : 0.f;
            } else {
                e[r] = __builtin_amdgcn_exp2f(s[r] * cfl[dd]);
            }
            z += e[r];
        }
        unsigned A0 = cvtpk(e[0], e[1]),  B0 = cvtpk(e[2], e[3]);
        unsigned C0 = cvtpk(e[4], e[5]),  D0 = cvtpk(e[6], e[7]);
        unsigned E0 = cvtpk(e[8], e[9]),  F0 = cvtpk(e[10], e[11]);
        unsigned G0 = cvtpk(e[12], e[13]), H0 = cvtpk(e[14], e[15]);
        plswap(A0, C0); plswap(B0, D0); plswap(E0, G0); plswap(F0, H0);
        union U { unsigned u[4]; short8 s8; };
        U p0, p1;
        p0.u[0] = A0; p0.u[1] = B0; p0.u[2] = C0; p0.u[3] = D0;
        p1.u[0] = E0; p1.u[1] = F0; p1.u[2] = G0; p1.u[3] = H0;
        const char* vp = vbase + buf * 8192;
        short8 v00 = *(const short8*)(vp + vby0[0]);
        short8 v01 = *(const short8*)(vp + vby0[1]);
        short8 v10 = *(const short8*)(vp + vby1[0]);
        short8 v11 = *(const short8*)(vp + vby1[1]);
        __builtin_amdgcn_s_setprio(1);
        acc0 = __builtin_amdgcn_mfma_f32_32x32x16_bf16(v00, p0.s8, acc0, 0, 0, 0);
        acc0 = __builtin_amdgcn_mfma_f32_32x32x16_bf16(v01, p1.s8, acc0, 0, 0, 0);
        acc1 = __builtin_amdgcn_mfma_f32_32x32x16_bf16(v10, p0.s8, acc1, 0, 0, 0);
        acc1 = __builtin_amdgcn_mfma_f32_32x32x16_bf16(v11, p1.s8, acc1, 0, 0, 0);
        __builtin_amdgcn_s_setprio(0);
    };

    int nt = tq + 1;
    stage(0, 0);
    __syncthreads();   // full drain once: buf0 + cfl + qf resolved
    int cur = 0;
    for (int it = 0; it < nt - 1; ++it) {
        stage(cur ^ 1, (it + 1) * 64);
        WAITVM(4);
        SBAR();
        body(cur, it * 64, BoolC<false>{});
        SBAR();
        cur ^= 1;
    }
    WAITVM(0);
    SBAR();
    // diagonal tile: qs>js full, qs==js triangular, qs<js all-masked (skip)
    if (qs > js)      body(cur, (nt - 1) * 64, BoolC<false>{});
    else if (qs == js) body(cur, (nt - 1) * 64, BoolC<true>{});
    __syncthreads();

    z += __shfl_xor(z, 32);
    float* osc = (float*)&kT[0][0][0];
    float* zbuf = (float*)&vT[0][0][0];
    if (js == 0) {
        float* o = osc + qs * 2048;
        #pragma unroll
        for (int r = 0; r < 16; ++r) {
            o[r * 64 + lane] = acc0[r];
            o[(16 + r) * 64 + lane] = acc1[r];
        }
        if (lane < 32) zbuf[qs * 32 + ql] = z;
    }
    __syncthreads();
    if (js == 1) {
        float zt = z + zbuf[qs * 32 + ql];
        float invz = 1.f / zt;
        const float* o = osc + qs * 2048;
        #pragma unroll
        for (int r = 0; r < 16; ++r) {
            acc0[r] = (acc0[r] + o[r * 64 + lane]) * invz;
            acc1[r] = (acc1[r] + o[(16 + r) * 64 + lane]) * invz;
        }
        int t = qb + qs * 32 + ql;
        unsigned short* yp = yb + (((size_t)b * T_ + t) * H_ + h) * 64;
        #pragma unroll
        for (int g = 0; g < 4; ++g) {
            uint2 st0, st1;
            st0.x = cvtpk(acc0[g * 4 + 0], acc0[g * 4 + 1]);
            st0.y = cvtpk(acc0[g * 4 + 2], acc0[g * 4 + 3]);
            *(uint2*)(yp + g * 8 + 4 * hl) = st0;
            st1.x = cvtpk(acc1[g * 4 + 0], acc1[g * 4 + 1]);
            st1.y = cvtpk(acc1[g * 4 + 2], acc1[g * 4 + 3]);
            *(uint2*)(yp + 32 + g * 8 + 4 * hl) = st1;
        }
    }
}

extern "C" void kernel_launch(void* const* d_in, const int* in_sizes, int n_in,
                              void* d_out, int out_size, void* d_ws, size_t ws_size,
                              hipStream_t stream) {
    const float* x    = (const float*)d_in[0];
    const float* cosb = (const float*)d_in[1];
    const float* sinb = (const float*)d_in[2];
    const float* Wq   = (const float*)d_in[3];
    const float* Wk   = (const float*)d_in[4];
    const float* Wv   = (const float*)d_in[5];
    const float* Wo   = (const float*)d_in[6];
    const float* beta = (const float*)d_in[7];
    float* out = (float*)d_out;

    char* ws = (char*)d_ws;
    unsigned short* xb   = (unsigned short*)(ws + 0);
    unsigned short* wqkv = (unsigned short*)(ws + 6291456);
    unsigned short* wob  = (unsigned short*)(ws + 9830400);
    unsigned short* qbf  = (unsigned short*)(ws + 11010048);
    unsigned short* kbf  = (unsigned short*)(ws + 17301504);
    unsigned short* vt   = (unsigned short*)(ws + 23592960);
    unsigned short* yb   = (unsigned short*)(ws + 29884416);
    float*          coh  = (float*)(ws + 36175872);

    convert_all_kernel<<<5384, 256, 0, stream>>>(x, Wq, Wk, Wv, Wo, xb, wqkv, wob, coh);

    dim3 gq(32, 36);
    gemm_qkv_kernel<<<gq, 256, 0, stream>>>(xb, wqkv, cosb, sinb, qbf, kbf, vt);

    attn_flash_kernel<<<B_ * H_ * (T_ / 64), 256, 0, stream>>>(qbf, kbf, vt, coh, beta, yb);

    dim3 go(64, 12);
    gemm_out_kernel<<<go, 256, 0, stream>>>(yb, wob, out);
}